// Round 2
// baseline (1925.700 us; speedup 1.0000x reference)
//
#include <hip/hip_runtime.h>
#include <hip/hip_bf16.h>

#define NN 8192
#define DIN 512
#define DH 256
#define DO_ 128
#define NCLS 8
#define NE 262144

typedef __attribute__((ext_vector_type(8))) short bf16x8;
typedef __attribute__((ext_vector_type(4))) float f32x4;
typedef __attribute__((ext_vector_type(4))) unsigned short u16x4;

__device__ __forceinline__ unsigned short f2bf(float x) {
    unsigned int u = __float_as_uint(x);
    return (unsigned short)((u + 0x7FFFu + ((u >> 16) & 1u)) >> 16);
}
__device__ __forceinline__ float bf2f(unsigned short h) {
    return __uint_as_float((unsigned int)h << 16);
}

// ---------------- f32 -> bf16 convert (vectorized, grid-stride) ----------------
__global__ void k_cvt_bf16(const float* __restrict__ in, unsigned short* __restrict__ out, int n4) {
    int i = blockIdx.x * blockDim.x + threadIdx.x;
    int stride = gridDim.x * blockDim.x;
    for (; i < n4; i += stride) {
        float4 v = ((const float4*)in)[i];
        u16x4 o;
        o.x = f2bf(v.x); o.y = f2bf(v.y); o.z = f2bf(v.z); o.w = f2bf(v.w);
        ((u16x4*)out)[i] = o;
    }
}

// ---------- f32 -> split bf16 hi/lo (A = hi + lo, rel err ~2^-17) ----------
__global__ void k_cvt_split(const float* __restrict__ in, unsigned short* __restrict__ hi,
                            unsigned short* __restrict__ lo, int n4) {
    int i = blockIdx.x * blockDim.x + threadIdx.x;
    int stride = gridDim.x * blockDim.x;
    for (; i < n4; i += stride) {
        float4 v = ((const float4*)in)[i];
        u16x4 oh, ol;
        oh.x = f2bf(v.x); ol.x = f2bf(v.x - bf2f(oh.x));
        oh.y = f2bf(v.y); ol.y = f2bf(v.y - bf2f(oh.y));
        oh.z = f2bf(v.z); ol.z = f2bf(v.z - bf2f(oh.z));
        oh.w = f2bf(v.w); ol.w = f2bf(v.w - bf2f(oh.w));
        ((u16x4*)hi)[i] = oh;
        ((u16x4*)lo)[i] = ol;
    }
}

// -- effT[j][i] = sum_k w[i][k]*tao[k][j], stored as split bf16 hi/lo, transposed --
__global__ void k_eff_split(const float* __restrict__ w, const float* __restrict__ tao,
                            unsigned short* __restrict__ effTh, unsigned short* __restrict__ effTl,
                            int I, int K0, int J) {
    int idx = blockIdx.x * blockDim.x + threadIdx.x;
    if (idx >= I * J) return;
    int i = idx % I, j = idx / I;
    float s = 0.f;
    for (int k = 0; k < K0; ++k) s += w[i * K0 + k] * tao[k * J + j];
    unsigned short h = f2bf(s);
    effTh[j * I + i] = h;
    effTl[j * I + i] = f2bf(s - bf2f(h));
}

#define GLDS(gp, lp) __builtin_amdgcn_global_load_lds( \
    (const __attribute__((address_space(1))) void*)(gp), \
    (__attribute__((address_space(3))) void*)(lp), 16, 0, 0)

// ---------------- single-bf16 MFMA GEMM, split-K partial out ----------------
// C_part[z][M][N] f32. BM=BN=128, BK=32, 4 waves.
__global__ __launch_bounds__(256) void k_gemm_part(
    const unsigned short* __restrict__ A, const unsigned short* __restrict__ B,
    float* __restrict__ C, int M, int N, int K, int kPerSplit)
{
    __shared__ unsigned short As[128 * 32];
    __shared__ unsigned short Bs[128 * 32];
    const int t = threadIdx.x;
    const int w = t >> 6;
    const int l = t & 63;
    const int wr = (w >> 1) * 64;
    const int wc = (w & 1) * 64;
    const long row0 = (long)blockIdx.x * 128;
    const long col0 = (long)blockIdx.y * 128;
    const long kbeg = (long)blockIdx.z * kPerSplit;
    const int nk = kPerSplit >> 5;

    f32x4 acc[4][4];
#pragma unroll
    for (int mi = 0; mi < 4; ++mi)
#pragma unroll
        for (int ni = 0; ni < 4; ++ni) {
            f32x4 z = {0.f, 0.f, 0.f, 0.f};
            acc[mi][ni] = z;
        }

    const int srow = (w << 4) + (l >> 2);
    const int skk  = (l & 3) << 3;
    const unsigned short* Abase = A + row0 * K + kbeg + skk;
    const unsigned short* Bbase = B + col0 * K + kbeg + skk;
    unsigned short* AsW = &As[w << 9];
    unsigned short* BsW = &Bs[w << 9];

    for (int kt = 0; kt < nk; ++kt) {
        const long ko = (long)kt << 5;
        __syncthreads();
        GLDS(Abase + (long)srow * K + ko,        AsW);
        GLDS(Abase + (long)(srow + 64) * K + ko, AsW + 2048);
        GLDS(Bbase + (long)srow * K + ko,        BsW);
        GLDS(Bbase + (long)(srow + 64) * K + ko, BsW + 2048);
        __syncthreads();

        const int ro  = (l & 15);
        const int kof = (l >> 4) << 3;
        bf16x8 a[4], b[4];
#pragma unroll
        for (int mi = 0; mi < 4; ++mi)
            a[mi] = *(const bf16x8*)&As[(wr + mi * 16 + ro) * 32 + kof];
#pragma unroll
        for (int ni = 0; ni < 4; ++ni)
            b[ni] = *(const bf16x8*)&Bs[(wc + ni * 16 + ro) * 32 + kof];
#pragma unroll
        for (int mi = 0; mi < 4; ++mi)
#pragma unroll
            for (int ni = 0; ni < 4; ++ni)
                acc[mi][ni] = __builtin_amdgcn_mfma_f32_16x16x32_bf16(a[mi], b[ni], acc[mi][ni], 0, 0, 0);
    }

    float* Cp = C + (long)blockIdx.z * M * N;
#pragma unroll
    for (int mi = 0; mi < 4; ++mi)
#pragma unroll
        for (int ni = 0; ni < 4; ++ni) {
            const long col = col0 + wc + ni * 16 + (l & 15);
            const long rbase = row0 + wr + mi * 16 + ((l >> 4) << 2);
            f32x4 v = acc[mi][ni];
#pragma unroll
            for (int j = 0; j < 4; ++j) Cp[(rbase + j) * N + col] = v[j];
        }
}

// ------------- split-bf16 3-term MFMA GEMM (≈fp32 precision) -------------
// C = (Ah+Al)@(Bh+Bl)^T dropping Al*Bl. OUT_MODE: 0 = f32 [M,N]; 2 = bf16 [N,M].
template<int OUT_MODE>
__global__ __launch_bounds__(256) void k_gemm_split(
    const unsigned short* __restrict__ Ah, const unsigned short* __restrict__ Al,
    const unsigned short* __restrict__ Bh, const unsigned short* __restrict__ Bl,
    void* __restrict__ C, int M, int N, int K)
{
    __shared__ unsigned short AsH[128 * 32];
    __shared__ unsigned short AsL[128 * 32];
    __shared__ unsigned short BsH[128 * 32];
    __shared__ unsigned short BsL[128 * 32];
    const int t = threadIdx.x;
    const int w = t >> 6;
    const int l = t & 63;
    const int wr = (w >> 1) * 64;
    const int wc = (w & 1) * 64;
    const long row0 = (long)blockIdx.x * 128;
    const long col0 = (long)blockIdx.y * 128;
    const int nk = K >> 5;

    f32x4 acc[4][4];
#pragma unroll
    for (int mi = 0; mi < 4; ++mi)
#pragma unroll
        for (int ni = 0; ni < 4; ++ni) {
            f32x4 z = {0.f, 0.f, 0.f, 0.f};
            acc[mi][ni] = z;
        }

    const int srow = (w << 4) + (l >> 2);
    const int skk  = (l & 3) << 3;
    const long aoff = row0 * K + skk;
    const long boff = col0 * K + skk;
    unsigned short* AsHW = &AsH[w << 9];
    unsigned short* AsLW = &AsL[w << 9];
    unsigned short* BsHW = &BsH[w << 9];
    unsigned short* BsLW = &BsL[w << 9];

    for (int kt = 0; kt < nk; ++kt) {
        const long ko = (long)kt << 5;
        __syncthreads();
        GLDS(Ah + aoff + (long)srow * K + ko,        AsHW);
        GLDS(Ah + aoff + (long)(srow + 64) * K + ko, AsHW + 2048);
        GLDS(Al + aoff + (long)srow * K + ko,        AsLW);
        GLDS(Al + aoff + (long)(srow + 64) * K + ko, AsLW + 2048);
        GLDS(Bh + boff + (long)srow * K + ko,        BsHW);
        GLDS(Bh + boff + (long)(srow + 64) * K + ko, BsHW + 2048);
        GLDS(Bl + boff + (long)srow * K + ko,        BsLW);
        GLDS(Bl + boff + (long)(srow + 64) * K + ko, BsLW + 2048);
        __syncthreads();

        const int ro  = (l & 15);
        const int kof = (l >> 4) << 3;
        bf16x8 ah[4], al[4], bh[4], bl[4];
#pragma unroll
        for (int mi = 0; mi < 4; ++mi) {
            ah[mi] = *(const bf16x8*)&AsH[(wr + mi * 16 + ro) * 32 + kof];
            al[mi] = *(const bf16x8*)&AsL[(wr + mi * 16 + ro) * 32 + kof];
        }
#pragma unroll
        for (int ni = 0; ni < 4; ++ni) {
            bh[ni] = *(const bf16x8*)&BsH[(wc + ni * 16 + ro) * 32 + kof];
            bl[ni] = *(const bf16x8*)&BsL[(wc + ni * 16 + ro) * 32 + kof];
        }
#pragma unroll
        for (int mi = 0; mi < 4; ++mi)
#pragma unroll
            for (int ni = 0; ni < 4; ++ni) {
                acc[mi][ni] = __builtin_amdgcn_mfma_f32_16x16x32_bf16(ah[mi], bl[ni], acc[mi][ni], 0, 0, 0);
                acc[mi][ni] = __builtin_amdgcn_mfma_f32_16x16x32_bf16(al[mi], bh[ni], acc[mi][ni], 0, 0, 0);
                acc[mi][ni] = __builtin_amdgcn_mfma_f32_16x16x32_bf16(ah[mi], bh[ni], acc[mi][ni], 0, 0, 0);
            }
    }

#pragma unroll
    for (int mi = 0; mi < 4; ++mi)
#pragma unroll
        for (int ni = 0; ni < 4; ++ni) {
            const long col = col0 + wc + ni * 16 + (l & 15);
            const long rbase = row0 + wr + mi * 16 + ((l >> 4) << 2);
            f32x4 v = acc[mi][ni];
            if (OUT_MODE == 0) {
                float* Cp = (float*)C;
#pragma unroll
                for (int j = 0; j < 4; ++j) Cp[(rbase + j) * N + col] = v[j];
            } else {
                u16x4 o;
                o.x = f2bf(v[0]); o.y = f2bf(v[1]); o.z = f2bf(v[2]); o.w = f2bf(v[3]);
                *(u16x4*)((unsigned short*)C + col * M + rbase) = o;
            }
        }
}

// ------------- split-K combine: sum partials, +bias, relu -------------
// OM: 0 = f32 out; 1 = split bf16 hi/lo out
template<int OM>
__global__ void k_combine(const float* __restrict__ part, void* __restrict__ out,
                          void* __restrict__ out2, const float* __restrict__ bias,
                          int M, int N, int Z) {
    int idx = blockIdx.x * blockDim.x + threadIdx.x;
    int n4 = N >> 2;
    if (idx >= M * n4) return;
    int m = idx / n4, c = idx % n4;
    float4 s = make_float4(0.f, 0.f, 0.f, 0.f);
    for (int z = 0; z < Z; ++z) {
        float4 p = *(const float4*)&part[((long)z * M + m) * N + (c << 2)];
        s.x += p.x; s.y += p.y; s.z += p.z; s.w += p.w;
    }
    float4 b = *(const float4*)&bias[c << 2];
    s.x = fmaxf(s.x + b.x, 0.f);
    s.y = fmaxf(s.y + b.y, 0.f);
    s.z = fmaxf(s.z + b.z, 0.f);
    s.w = fmaxf(s.w + b.w, 0.f);
    if (OM == 0) {
        *(float4*)((float*)out + (long)m * N + (c << 2)) = s;
    } else {
        u16x4 oh, ol;
        oh.x = f2bf(s.x); ol.x = f2bf(s.x - bf2f(oh.x));
        oh.y = f2bf(s.y); ol.y = f2bf(s.y - bf2f(oh.y));
        oh.z = f2bf(s.z); ol.z = f2bf(s.z - bf2f(oh.z));
        oh.w = f2bf(s.w); ol.w = f2bf(s.w - bf2f(oh.w));
        *(u16x4*)((unsigned short*)out  + (long)m * N + (c << 2)) = oh;
        *(u16x4*)((unsigned short*)out2 + (long)m * N + (c << 2)) = ol;
    }
}

// ---------------- edge scatter: agg[dst] += h[src] * norm[src] ----------------
__global__ void k_scatter(const float* __restrict__ h, const int* __restrict__ src,
                          const int* __restrict__ dstv, const float* __restrict__ norm,
                          float* __restrict__ agg, int d4) {
    int idx = blockIdx.x * blockDim.x + threadIdx.x;
    int e = idx / d4;
    int c = idx % d4;
    if (e >= NE) return;
    int s = src[e], d = dstv[e];
    float ns = norm[s];
    float4 hv = *(const float4*)&h[((long)s * d4 + c) << 2];
    float* ap = &agg[((long)d * d4 + c) << 2];
    unsafeAtomicAdd(ap + 0, hv.x * ns);
    unsafeAtomicAdd(ap + 1, hv.y * ns);
    unsafeAtomicAdd(ap + 2, hv.z * ns);
    unsafeAtomicAdd(ap + 3, hv.w * ns);
}

// ------------- prop finalize: relu(agg*norm[dst] + bias) -------------
// OM: 0 = f32 out; 1 = split bf16 hi/lo out
template<int OM>
__global__ void k_prop_fin(const float* __restrict__ agg, const float* __restrict__ norm,
                           const float* __restrict__ bias, void* __restrict__ out,
                           void* __restrict__ out2, int d4) {
    int idx = blockIdx.x * blockDim.x + threadIdx.x;
    if (idx >= NN * d4) return;
    int i = idx / d4, c = idx % d4;
    float nv = norm[i];
    float4 a = *(const float4*)&agg[((long)i * d4 + c) << 2];
    float4 b = *(const float4*)&bias[c << 2];
    float4 r;
    r.x = fmaxf(a.x * nv + b.x, 0.f);
    r.y = fmaxf(a.y * nv + b.y, 0.f);
    r.z = fmaxf(a.z * nv + b.z, 0.f);
    r.w = fmaxf(a.w * nv + b.w, 0.f);
    if (OM == 0) {
        *(float4*)((float*)out + ((long)i * d4 + c) * 4) = r;
    } else {
        u16x4 oh, ol;
        oh.x = f2bf(r.x); ol.x = f2bf(r.x - bf2f(oh.x));
        oh.y = f2bf(r.y); ol.y = f2bf(r.y - bf2f(oh.y));
        oh.z = f2bf(r.z); ol.z = f2bf(r.z - bf2f(oh.z));
        oh.w = f2bf(r.w); ol.w = f2bf(r.w - bf2f(oh.w));
        *(u16x4*)((unsigned short*)out  + ((long)i * d4 + c) * 4) = oh;
        *(u16x4*)((unsigned short*)out2 + ((long)i * d4 + c) * 4) = ol;
    }
}

// ------------- attention fusion + classifier (one wave per row) -------------
__global__ __launch_bounds__(256) void k_attn(
    const float* __restrict__ HL, const float* __restrict__ HG,
    const float* __restrict__ Wa, const float* __restrict__ Wc,
    const float* __restrict__ bc, float* __restrict__ out) {
    int wv = threadIdx.x >> 6, l = threadIdx.x & 63;
    int row = blockIdx.x * 4 + wv;
    float2 hl = *(const float2*)&HL[(long)row * DO_ + l * 2];
    float2 hg = *(const float2*)&HG[(long)row * DO_ + l * 2];
    float4 wa0 = *(const float4*)&Wa[(2 * l) * 2];
    float4 wa1 = *(const float4*)&Wa[(DO_ + 2 * l) * 2];
    float p0 = hl.x * wa0.x + hl.y * wa0.z + hg.x * wa1.x + hg.y * wa1.z;
    float p1 = hl.x * wa0.y + hl.y * wa0.w + hg.x * wa1.y + hg.y * wa1.w;
#pragma unroll
    for (int off = 32; off >= 1; off >>= 1) {
        p0 += __shfl_xor(p0, off);
        p1 += __shfl_xor(p1, off);
    }
    float mx = fmaxf(p0, p1);
    float e0 = __expf(p0 - mx), e1 = __expf(p1 - mx);
    float inv = 1.f / (e0 + e1);
    float a0 = e0 * inv, a1 = e1 * inv;
    float z0 = a0 * hl.x + a1 * hg.x;
    float z1 = a0 * hl.y + a1 * hg.y;
    float4 wcA0 = *(const float4*)&Wc[(2 * l) * NCLS];
    float4 wcA1 = *(const float4*)&Wc[(2 * l) * NCLS + 4];
    float4 wcB0 = *(const float4*)&Wc[(2 * l + 1) * NCLS];
    float4 wcB1 = *(const float4*)&Wc[(2 * l + 1) * NCLS + 4];
    float q0 = z0 * wcA0.x + z1 * wcB0.x;
    float q1 = z0 * wcA0.y + z1 * wcB0.y;
    float q2 = z0 * wcA0.z + z1 * wcB0.z;
    float q3 = z0 * wcA0.w + z1 * wcB0.w;
    float q4 = z0 * wcA1.x + z1 * wcB1.x;
    float q5 = z0 * wcA1.y + z1 * wcB1.y;
    float q6 = z0 * wcA1.z + z1 * wcB1.z;
    float q7 = z0 * wcA1.w + z1 * wcB1.w;
#pragma unroll
    for (int off = 32; off >= 1; off >>= 1) {
        q0 += __shfl_xor(q0, off); q1 += __shfl_xor(q1, off);
        q2 += __shfl_xor(q2, off); q3 += __shfl_xor(q3, off);
        q4 += __shfl_xor(q4, off); q5 += __shfl_xor(q5, off);
        q6 += __shfl_xor(q6, off); q7 += __shfl_xor(q7, off);
    }
    if (l == 0) {
        float* o = &out[(long)row * NCLS];
        o[0] = q0 + bc[0]; o[1] = q1 + bc[1]; o[2] = q2 + bc[2]; o[3] = q3 + bc[3];
        o[4] = q4 + bc[4]; o[5] = q5 + bc[5]; o[6] = q6 + bc[6]; o[7] = q7 + bc[7];
    }
}

extern "C" void kernel_launch(void* const* d_in, const int* in_sizes, int n_in,
                              void* d_out, int out_size, void* d_ws, size_t ws_size,
                              hipStream_t stream) {
    (void)in_sizes; (void)n_in; (void)out_size; (void)ws_size;
    const float* feats = (const float*)d_in[0];
    const float* norm  = (const float*)d_in[1];
    const float* tao1L = (const float*)d_in[2];
    const float* tao2L = (const float*)d_in[3];
    const float* tao1G = (const float*)d_in[4];
    const float* tao2G = (const float*)d_in[5];
    const float* PPMI  = (const float*)d_in[6];
    const float* w1  = (const float*)d_in[7];
    const float* b1  = (const float*)d_in[8];
    const float* w2  = (const float*)d_in[9];
    const float* b2  = (const float*)d_in[10];
    const float* w1g = (const float*)d_in[11];
    const float* b1g = (const float*)d_in[12];
    const float* w2g = (const float*)d_in[13];
    const float* b2g = (const float*)d_in[14];
    const float* Wa  = (const float*)d_in[15];
    const float* Wc  = (const float*)d_in[16];
    const float* bc  = (const float*)d_in[17];
    const int* src = (const int*)d_in[18];
    const int* dst = (const int*)d_in[19];

    char* ws = (char*)d_ws;
    size_t off = 0;
    auto alloc = [&](size_t b) { void* p = (void*)(ws + off); off += (b + 255) & ~(size_t)255; return p; };
    unsigned short* ppmi_bf = (unsigned short*)alloc((size_t)NN * NN * 2);     // 134 MB
    unsigned short* fh = (unsigned short*)alloc((size_t)NN * DIN * 2);
    unsigned short* fl = (unsigned short*)alloc((size_t)NN * DIN * 2);
    unsigned short* w1lh = (unsigned short*)alloc((size_t)DH * DIN * 2);
    unsigned short* w1ll = (unsigned short*)alloc((size_t)DH * DIN * 2);
    unsigned short* w2lh = (unsigned short*)alloc((size_t)DO_ * DH * 2);
    unsigned short* w2ll = (unsigned short*)alloc((size_t)DO_ * DH * 2);
    unsigned short* w1gh = (unsigned short*)alloc((size_t)DH * DIN * 2);
    unsigned short* w1gl = (unsigned short*)alloc((size_t)DH * DIN * 2);
    unsigned short* w2gh = (unsigned short*)alloc((size_t)DO_ * DH * 2);
    unsigned short* w2gl = (unsigned short*)alloc((size_t)DO_ * DH * 2);
    unsigned short* g0t = (unsigned short*)alloc((size_t)DH * NN * 2);         // (feats@W1g)^T bf16
    unsigned short* g2h = (unsigned short*)alloc((size_t)NN * DH * 2);
    unsigned short* g2l = (unsigned short*)alloc((size_t)NN * DH * 2);
    unsigned short* g3t = (unsigned short*)alloc((size_t)DO_ * NN * 2);        // (g2@W2g)^T bf16
    unsigned short* h1h = (unsigned short*)alloc((size_t)NN * DH * 2);
    unsigned short* h1l = (unsigned short*)alloc((size_t)NN * DH * 2);
    float* HL  = (float*)alloc((size_t)NN * DO_ * 4);
    float* HG  = (float*)alloc((size_t)NN * DO_ * 4);
    float* agg = (float*)alloc((size_t)NN * DH * 4);
    // big region reused sequentially: local h0/h2 first, then split-K partials
    char* big = (char*)alloc((size_t)8 * NN * DO_ * 4);                        // 33.5 MB
    float* h0 = (float*)big;                       // NN*DH*4 = 8.4 MB
    float* h2 = (float*)(big + (size_t)NN * DH * 4); // NN*DO_*4 = 4.2 MB
    float* part = (float*)big;

    // conversions
    k_cvt_bf16<<<dim3(8192), dim3(256), 0, stream>>>(PPMI, ppmi_bf, NN * NN / 4);
    k_cvt_split<<<dim3(2048), dim3(256), 0, stream>>>(feats, fh, fl, NN * DIN / 4);

    // effective weights (split bf16, transposed)
    k_eff_split<<<dim3((DIN * DH + 255) / 256), dim3(256), 0, stream>>>(w1,  tao1L, w1lh, w1ll, DIN, DH, DH);
    k_eff_split<<<dim3((DH * DO_ + 255) / 256), dim3(256), 0, stream>>>(w2,  tao2L, w2lh, w2ll, DH, DO_, DO_);
    k_eff_split<<<dim3((DIN * DH + 255) / 256), dim3(256), 0, stream>>>(w1g, tao1G, w1gh, w1gl, DIN, DH, DH);
    k_eff_split<<<dim3((DH * DO_ + 255) / 256), dim3(256), 0, stream>>>(w2g, tao2G, w2gh, w2gl, DH, DO_, DO_);

    // ---- local branch (all ≈fp32 precision) ----
    k_gemm_split<0><<<dim3(64, 2), dim3(256), 0, stream>>>(fh, fl, w1lh, w1ll, h0, NN, DH, DIN);
    hipMemsetAsync(agg, 0, (size_t)NN * DH * 4, stream);
    k_scatter<<<dim3(NE * 64 / 256), dim3(256), 0, stream>>>(h0, src, dst, norm, agg, 64);
    k_prop_fin<1><<<dim3(NN * 64 / 256), dim3(256), 0, stream>>>(agg, norm, b1, h1h, h1l, 64);
    k_gemm_split<0><<<dim3(64, 1), dim3(256), 0, stream>>>(h1h, h1l, w2lh, w2ll, h2, NN, DO_, DH);
    hipMemsetAsync(agg, 0, (size_t)NN * DO_ * 4, stream);
    k_scatter<<<dim3(NE * 32 / 256), dim3(256), 0, stream>>>(h2, src, dst, norm, agg, 32);
    k_prop_fin<0><<<dim3(NN * 32 / 256), dim3(256), 0, stream>>>(agg, norm, b2, HL, nullptr, 32);

    // ---- global branch (PPMI GEMMs single-bf16: results are O(0.01), err negligible) ----
    k_gemm_split<2><<<dim3(64, 2), dim3(256), 0, stream>>>(fh, fl, w1gh, w1gl, g0t, NN, DH, DIN);
    k_gemm_part<<<dim3(64, 2, 4), dim3(256), 0, stream>>>(ppmi_bf, g0t, part, NN, DH, NN, NN / 4);
    k_combine<1><<<dim3(NN * DH / 4 / 256), dim3(256), 0, stream>>>(part, g2h, g2l, b1g, NN, DH, 4);
    k_gemm_split<2><<<dim3(64, 1), dim3(256), 0, stream>>>(g2h, g2l, w2gh, w2gl, g3t, NN, DO_, DH);
    k_gemm_part<<<dim3(64, 1, 8), dim3(256), 0, stream>>>(ppmi_bf, g3t, part, NN, DO_, NN, NN / 8);
    k_combine<0><<<dim3(NN * DO_ / 4 / 256), dim3(256), 0, stream>>>(part, HG, nullptr, b2g, NN, DO_, 8);

    // ---- attention fusion + classifier ----
    k_attn<<<dim3(NN / 4), dim3(256), 0, stream>>>(HL, HG, Wa, Wc, bc, (float*)d_out);
}

// Round 3
// 703.043 us; speedup vs baseline: 2.7391x; 2.7391x over previous
//
#include <hip/hip_runtime.h>
#include <hip/hip_bf16.h>

#define NN 8192
#define DIN 512
#define DH 256
#define DO_ 128
#define NCLS 8
#define NE 262144

typedef __attribute__((ext_vector_type(8))) short bf16x8;
typedef __attribute__((ext_vector_type(4))) float f32x4;
typedef __attribute__((ext_vector_type(4))) unsigned short u16x4;

__device__ __forceinline__ unsigned short f2bf(float x) {
    unsigned int u = __float_as_uint(x);
    return (unsigned short)((u + 0x7FFFu + ((u >> 16) & 1u)) >> 16);
}
__device__ __forceinline__ float bf2f(unsigned short h) {
    return __uint_as_float((unsigned int)h << 16);
}

// ---------------- f32 -> bf16 convert (vectorized, grid-stride) ----------------
__global__ void k_cvt_bf16(const float* __restrict__ in, unsigned short* __restrict__ out, int n4) {
    int i = blockIdx.x * blockDim.x + threadIdx.x;
    int stride = gridDim.x * blockDim.x;
    for (; i < n4; i += stride) {
        float4 v = ((const float4*)in)[i];
        u16x4 o;
        o.x = f2bf(v.x); o.y = f2bf(v.y); o.z = f2bf(v.z); o.w = f2bf(v.w);
        ((u16x4*)out)[i] = o;
    }
}

// ---------- f32 -> split bf16 hi/lo (A = hi + lo, rel err ~2^-17) ----------
__global__ void k_cvt_split(const float* __restrict__ in, unsigned short* __restrict__ hi,
                            unsigned short* __restrict__ lo, int n4) {
    int i = blockIdx.x * blockDim.x + threadIdx.x;
    int stride = gridDim.x * blockDim.x;
    for (; i < n4; i += stride) {
        float4 v = ((const float4*)in)[i];
        u16x4 oh, ol;
        oh.x = f2bf(v.x); ol.x = f2bf(v.x - bf2f(oh.x));
        oh.y = f2bf(v.y); ol.y = f2bf(v.y - bf2f(oh.y));
        oh.z = f2bf(v.z); ol.z = f2bf(v.z - bf2f(oh.z));
        oh.w = f2bf(v.w); ol.w = f2bf(v.w - bf2f(oh.w));
        ((u16x4*)hi)[i] = oh;
        ((u16x4*)lo)[i] = ol;
    }
}

// -- effT[j][i] = sum_k w[i][k]*tao[k][j], stored as split bf16 hi/lo, transposed --
__global__ void k_eff_split(const float* __restrict__ w, const float* __restrict__ tao,
                            unsigned short* __restrict__ effTh, unsigned short* __restrict__ effTl,
                            int I, int K0, int J) {
    int idx = blockIdx.x * blockDim.x + threadIdx.x;
    if (idx >= I * J) return;
    int i = idx % I, j = idx / I;
    float s = 0.f;
    for (int k = 0; k < K0; ++k) s += w[i * K0 + k] * tao[k * J + j];
    unsigned short h = f2bf(s);
    effTh[j * I + i] = h;
    effTl[j * I + i] = f2bf(s - bf2f(h));
}

#define GLDS(gp, lp) __builtin_amdgcn_global_load_lds( \
    (const __attribute__((address_space(1))) void*)(gp), \
    (__attribute__((address_space(3))) void*)(lp), 16, 0, 0)

// ---------------- single-bf16 MFMA GEMM, split-K partial out ----------------
__global__ __launch_bounds__(256) void k_gemm_part(
    const unsigned short* __restrict__ A, const unsigned short* __restrict__ B,
    float* __restrict__ C, int M, int N, int K, int kPerSplit)
{
    __shared__ unsigned short As[128 * 32];
    __shared__ unsigned short Bs[128 * 32];
    const int t = threadIdx.x;
    const int w = t >> 6;
    const int l = t & 63;
    const int wr = (w >> 1) * 64;
    const int wc = (w & 1) * 64;
    const long row0 = (long)blockIdx.x * 128;
    const long col0 = (long)blockIdx.y * 128;
    const long kbeg = (long)blockIdx.z * kPerSplit;
    const int nk = kPerSplit >> 5;

    f32x4 acc[4][4];
#pragma unroll
    for (int mi = 0; mi < 4; ++mi)
#pragma unroll
        for (int ni = 0; ni < 4; ++ni) {
            f32x4 z = {0.f, 0.f, 0.f, 0.f};
            acc[mi][ni] = z;
        }

    const int srow = (w << 4) + (l >> 2);
    const int skk  = (l & 3) << 3;
    const unsigned short* Abase = A + row0 * K + kbeg + skk;
    const unsigned short* Bbase = B + col0 * K + kbeg + skk;
    unsigned short* AsW = &As[w << 9];
    unsigned short* BsW = &Bs[w << 9];

    for (int kt = 0; kt < nk; ++kt) {
        const long ko = (long)kt << 5;
        __syncthreads();
        GLDS(Abase + (long)srow * K + ko,        AsW);
        GLDS(Abase + (long)(srow + 64) * K + ko, AsW + 2048);
        GLDS(Bbase + (long)srow * K + ko,        BsW);
        GLDS(Bbase + (long)(srow + 64) * K + ko, BsW + 2048);
        __syncthreads();

        const int ro  = (l & 15);
        const int kof = (l >> 4) << 3;
        bf16x8 a[4], b[4];
#pragma unroll
        for (int mi = 0; mi < 4; ++mi)
            a[mi] = *(const bf16x8*)&As[(wr + mi * 16 + ro) * 32 + kof];
#pragma unroll
        for (int ni = 0; ni < 4; ++ni)
            b[ni] = *(const bf16x8*)&Bs[(wc + ni * 16 + ro) * 32 + kof];
#pragma unroll
        for (int mi = 0; mi < 4; ++mi)
#pragma unroll
            for (int ni = 0; ni < 4; ++ni)
                acc[mi][ni] = __builtin_amdgcn_mfma_f32_16x16x32_bf16(a[mi], b[ni], acc[mi][ni], 0, 0, 0);
    }

    float* Cp = C + (long)blockIdx.z * M * N;
#pragma unroll
    for (int mi = 0; mi < 4; ++mi)
#pragma unroll
        for (int ni = 0; ni < 4; ++ni) {
            const long col = col0 + wc + ni * 16 + (l & 15);
            const long rbase = row0 + wr + mi * 16 + ((l >> 4) << 2);
            f32x4 v = acc[mi][ni];
#pragma unroll
            for (int j = 0; j < 4; ++j) Cp[(rbase + j) * N + col] = v[j];
        }
}

// ------------- split-bf16 3-term MFMA GEMM (≈fp32 precision) -------------
// C = (Ah+Al)@(Bh+Bl)^T dropping Al*Bl. OUT_MODE: 0 = f32 [M,N]; 2 = bf16 [N,M].
template<int OUT_MODE>
__global__ __launch_bounds__(256) void k_gemm_split(
    const unsigned short* __restrict__ Ah, const unsigned short* __restrict__ Al,
    const unsigned short* __restrict__ Bh, const unsigned short* __restrict__ Bl,
    void* __restrict__ C, int M, int N, int K)
{
    __shared__ unsigned short AsH[128 * 32];
    __shared__ unsigned short AsL[128 * 32];
    __shared__ unsigned short BsH[128 * 32];
    __shared__ unsigned short BsL[128 * 32];
    const int t = threadIdx.x;
    const int w = t >> 6;
    const int l = t & 63;
    const int wr = (w >> 1) * 64;
    const int wc = (w & 1) * 64;
    const long row0 = (long)blockIdx.x * 128;
    const long col0 = (long)blockIdx.y * 128;
    const int nk = K >> 5;

    f32x4 acc[4][4];
#pragma unroll
    for (int mi = 0; mi < 4; ++mi)
#pragma unroll
        for (int ni = 0; ni < 4; ++ni) {
            f32x4 z = {0.f, 0.f, 0.f, 0.f};
            acc[mi][ni] = z;
        }

    const int srow = (w << 4) + (l >> 2);
    const int skk  = (l & 3) << 3;
    const long aoff = row0 * K + skk;
    const long boff = col0 * K + skk;
    unsigned short* AsHW = &AsH[w << 9];
    unsigned short* AsLW = &AsL[w << 9];
    unsigned short* BsHW = &BsH[w << 9];
    unsigned short* BsLW = &BsL[w << 9];

    for (int kt = 0; kt < nk; ++kt) {
        const long ko = (long)kt << 5;
        __syncthreads();
        GLDS(Ah + aoff + (long)srow * K + ko,        AsHW);
        GLDS(Ah + aoff + (long)(srow + 64) * K + ko, AsHW + 2048);
        GLDS(Al + aoff + (long)srow * K + ko,        AsLW);
        GLDS(Al + aoff + (long)(srow + 64) * K + ko, AsLW + 2048);
        GLDS(Bh + boff + (long)srow * K + ko,        BsHW);
        GLDS(Bh + boff + (long)(srow + 64) * K + ko, BsHW + 2048);
        GLDS(Bl + boff + (long)srow * K + ko,        BsLW);
        GLDS(Bl + boff + (long)(srow + 64) * K + ko, BsLW + 2048);
        __syncthreads();

        const int ro  = (l & 15);
        const int kof = (l >> 4) << 3;
        bf16x8 ah[4], al[4], bh[4], bl[4];
#pragma unroll
        for (int mi = 0; mi < 4; ++mi) {
            ah[mi] = *(const bf16x8*)&AsH[(wr + mi * 16 + ro) * 32 + kof];
            al[mi] = *(const bf16x8*)&AsL[(wr + mi * 16 + ro) * 32 + kof];
        }
#pragma unroll
        for (int ni = 0; ni < 4; ++ni) {
            bh[ni] = *(const bf16x8*)&BsH[(wc + ni * 16 + ro) * 32 + kof];
            bl[ni] = *(const bf16x8*)&BsL[(wc + ni * 16 + ro) * 32 + kof];
        }
#pragma unroll
        for (int mi = 0; mi < 4; ++mi)
#pragma unroll
            for (int ni = 0; ni < 4; ++ni) {
                acc[mi][ni] = __builtin_amdgcn_mfma_f32_16x16x32_bf16(ah[mi], bl[ni], acc[mi][ni], 0, 0, 0);
                acc[mi][ni] = __builtin_amdgcn_mfma_f32_16x16x32_bf16(al[mi], bh[ni], acc[mi][ni], 0, 0, 0);
                acc[mi][ni] = __builtin_amdgcn_mfma_f32_16x16x32_bf16(ah[mi], bh[ni], acc[mi][ni], 0, 0, 0);
            }
    }

#pragma unroll
    for (int mi = 0; mi < 4; ++mi)
#pragma unroll
        for (int ni = 0; ni < 4; ++ni) {
            const long col = col0 + wc + ni * 16 + (l & 15);
            const long rbase = row0 + wr + mi * 16 + ((l >> 4) << 2);
            f32x4 v = acc[mi][ni];
            if (OUT_MODE == 0) {
                float* Cp = (float*)C;
#pragma unroll
                for (int j = 0; j < 4; ++j) Cp[(rbase + j) * N + col] = v[j];
            } else {
                u16x4 o;
                o.x = f2bf(v[0]); o.y = f2bf(v[1]); o.z = f2bf(v[2]); o.w = f2bf(v[3]);
                *(u16x4*)((unsigned short*)C + col * M + rbase) = o;
            }
        }
}

// ------------- split-K combine: sum partials, +bias, relu -------------
// OM: 0 = f32 out; 1 = split bf16 hi/lo out
template<int OM>
__global__ void k_combine(const float* __restrict__ part, void* __restrict__ out,
                          void* __restrict__ out2, const float* __restrict__ bias,
                          int M, int N, int Z) {
    int idx = blockIdx.x * blockDim.x + threadIdx.x;
    int n4 = N >> 2;
    if (idx >= M * n4) return;
    int m = idx / n4, c = idx % n4;
    float4 s = make_float4(0.f, 0.f, 0.f, 0.f);
    for (int z = 0; z < Z; ++z) {
        float4 p = *(const float4*)&part[((long)z * M + m) * N + (c << 2)];
        s.x += p.x; s.y += p.y; s.z += p.z; s.w += p.w;
    }
    float4 b = *(const float4*)&bias[c << 2];
    s.x = fmaxf(s.x + b.x, 0.f);
    s.y = fmaxf(s.y + b.y, 0.f);
    s.z = fmaxf(s.z + b.z, 0.f);
    s.w = fmaxf(s.w + b.w, 0.f);
    if (OM == 0) {
        *(float4*)((float*)out + (long)m * N + (c << 2)) = s;
    } else {
        u16x4 oh, ol;
        oh.x = f2bf(s.x); ol.x = f2bf(s.x - bf2f(oh.x));
        oh.y = f2bf(s.y); ol.y = f2bf(s.y - bf2f(oh.y));
        oh.z = f2bf(s.z); ol.z = f2bf(s.z - bf2f(oh.z));
        oh.w = f2bf(s.w); ol.w = f2bf(s.w - bf2f(oh.w));
        *(u16x4*)((unsigned short*)out  + (long)m * N + (c << 2)) = oh;
        *(u16x4*)((unsigned short*)out2 + (long)m * N + (c << 2)) = ol;
    }
}

// ================= CSR build: histogram -> scan -> fill =================
__global__ void k_hist(const int* __restrict__ dstv, int* __restrict__ deg) {
    int e = blockIdx.x * blockDim.x + threadIdx.x;
    if (e < NE) atomicAdd(&deg[dstv[e]], 1);
}

// single block of 1024 threads, exclusive scan of 8192 degrees
__global__ __launch_bounds__(1024) void k_scan(const int* __restrict__ deg,
                                               int* __restrict__ rs, int* __restrict__ cur) {
    __shared__ int sums[1024];
    int t = threadIdx.x;
    int loc[8];
    int s = 0;
#pragma unroll
    for (int j = 0; j < 8; ++j) { loc[j] = deg[t * 8 + j]; s += loc[j]; }
    sums[t] = s;
    __syncthreads();
    for (int off = 1; off < 1024; off <<= 1) {
        int v = (t >= off) ? sums[t - off] : 0;
        __syncthreads();
        sums[t] += v;
        __syncthreads();
    }
    int base = (t > 0) ? sums[t - 1] : 0;
#pragma unroll
    for (int j = 0; j < 8; ++j) {
        rs[t * 8 + j] = base;
        cur[t * 8 + j] = base;
        base += loc[j];
    }
    if (t == 1023) rs[8192] = base;
}

__global__ void k_fill(const int* __restrict__ srcv, const int* __restrict__ dstv,
                       int* __restrict__ cur, int* __restrict__ csrc) {
    int e = blockIdx.x * blockDim.x + threadIdx.x;
    if (e >= NE) return;
    int pos = atomicAdd(&cur[dstv[e]], 1);
    csrc[pos] = srcv[e];
}

// ====== CSR gather prop, D=256: wave per dst row, lane owns float4 column ======
// out: relu(sum_{s in row} h[s]*norm[s] * norm[row] + bias) -> split bf16 hi/lo
__global__ __launch_bounds__(256) void k_gather256(
    const float* __restrict__ h, const int* __restrict__ rs, const int* __restrict__ csrc,
    const float* __restrict__ norm, const float* __restrict__ bias,
    unsigned short* __restrict__ outh, unsigned short* __restrict__ outl) {
    int wv = threadIdx.x >> 6, l = threadIdx.x & 63;
    int row = blockIdx.x * 4 + wv;
    int beg = rs[row], end = rs[row + 1];
    float4 acc = make_float4(0.f, 0.f, 0.f, 0.f);
    for (int i = beg; i < end; ++i) {
        int s = csrc[i];
        float ns = norm[s];
        float4 hv = *(const float4*)&h[((long)s << 8) + (l << 2)];
        acc.x += hv.x * ns; acc.y += hv.y * ns; acc.z += hv.z * ns; acc.w += hv.w * ns;
    }
    float nv = norm[row];
    float4 b = *(const float4*)&bias[l << 2];
    float4 r;
    r.x = fmaxf(acc.x * nv + b.x, 0.f);
    r.y = fmaxf(acc.y * nv + b.y, 0.f);
    r.z = fmaxf(acc.z * nv + b.z, 0.f);
    r.w = fmaxf(acc.w * nv + b.w, 0.f);
    u16x4 oh, ol;
    oh.x = f2bf(r.x); ol.x = f2bf(r.x - bf2f(oh.x));
    oh.y = f2bf(r.y); ol.y = f2bf(r.y - bf2f(oh.y));
    oh.z = f2bf(r.z); ol.z = f2bf(r.z - bf2f(oh.z));
    oh.w = f2bf(r.w); ol.w = f2bf(r.w - bf2f(oh.w));
    *(u16x4*)&outh[((long)row << 8) + (l << 2)] = oh;
    *(u16x4*)&outl[((long)row << 8) + (l << 2)] = ol;
}

// ====== CSR gather prop, D=128: wave per dst row, lane owns float2 column ======
// out: relu(... + bias) -> f32 (feeds attention)
__global__ __launch_bounds__(256) void k_gather128(
    const float* __restrict__ h, const int* __restrict__ rs, const int* __restrict__ csrc,
    const float* __restrict__ norm, const float* __restrict__ bias,
    float* __restrict__ out) {
    int wv = threadIdx.x >> 6, l = threadIdx.x & 63;
    int row = blockIdx.x * 4 + wv;
    int beg = rs[row], end = rs[row + 1];
    float2 acc = make_float2(0.f, 0.f);
    for (int i = beg; i < end; ++i) {
        int s = csrc[i];
        float ns = norm[s];
        float2 hv = *(const float2*)&h[((long)s << 7) + (l << 1)];
        acc.x += hv.x * ns; acc.y += hv.y * ns;
    }
    float nv = norm[row];
    float2 b = *(const float2*)&bias[l << 1];
    float2 r;
    r.x = fmaxf(acc.x * nv + b.x, 0.f);
    r.y = fmaxf(acc.y * nv + b.y, 0.f);
    *(float2*)&out[((long)row << 7) + (l << 1)] = r;
}

// ------------- attention fusion + classifier (one wave per row) -------------
__global__ __launch_bounds__(256) void k_attn(
    const float* __restrict__ HL, const float* __restrict__ HG,
    const float* __restrict__ Wa, const float* __restrict__ Wc,
    const float* __restrict__ bc, float* __restrict__ out) {
    int wv = threadIdx.x >> 6, l = threadIdx.x & 63;
    int row = blockIdx.x * 4 + wv;
    float2 hl = *(const float2*)&HL[(long)row * DO_ + l * 2];
    float2 hg = *(const float2*)&HG[(long)row * DO_ + l * 2];
    float4 wa0 = *(const float4*)&Wa[(2 * l) * 2];
    float4 wa1 = *(const float4*)&Wa[(DO_ + 2 * l) * 2];
    float p0 = hl.x * wa0.x + hl.y * wa0.z + hg.x * wa1.x + hg.y * wa1.z;
    float p1 = hl.x * wa0.y + hl.y * wa0.w + hg.x * wa1.y + hg.y * wa1.w;
#pragma unroll
    for (int off = 32; off >= 1; off >>= 1) {
        p0 += __shfl_xor(p0, off);
        p1 += __shfl_xor(p1, off);
    }
    float mx = fmaxf(p0, p1);
    float e0 = __expf(p0 - mx), e1 = __expf(p1 - mx);
    float inv = 1.f / (e0 + e1);
    float a0 = e0 * inv, a1 = e1 * inv;
    float z0 = a0 * hl.x + a1 * hg.x;
    float z1 = a0 * hl.y + a1 * hg.y;
    float4 wcA0 = *(const float4*)&Wc[(2 * l) * NCLS];
    float4 wcA1 = *(const float4*)&Wc[(2 * l) * NCLS + 4];
    float4 wcB0 = *(const float4*)&Wc[(2 * l + 1) * NCLS];
    float4 wcB1 = *(const float4*)&Wc[(2 * l + 1) * NCLS + 4];
    float q0 = z0 * wcA0.x + z1 * wcB0.x;
    float q1 = z0 * wcA0.y + z1 * wcB0.y;
    float q2 = z0 * wcA0.z + z1 * wcB0.z;
    float q3 = z0 * wcA0.w + z1 * wcB0.w;
    float q4 = z0 * wcA1.x + z1 * wcB1.x;
    float q5 = z0 * wcA1.y + z1 * wcB1.y;
    float q6 = z0 * wcA1.z + z1 * wcB1.z;
    float q7 = z0 * wcA1.w + z1 * wcB1.w;
#pragma unroll
    for (int off = 32; off >= 1; off >>= 1) {
        q0 += __shfl_xor(q0, off); q1 += __shfl_xor(q1, off);
        q2 += __shfl_xor(q2, off); q3 += __shfl_xor(q3, off);
        q4 += __shfl_xor(q4, off); q5 += __shfl_xor(q5, off);
        q6 += __shfl_xor(q6, off); q7 += __shfl_xor(q7, off);
    }
    if (l == 0) {
        float* o = &out[(long)row * NCLS];
        o[0] = q0 + bc[0]; o[1] = q1 + bc[1]; o[2] = q2 + bc[2]; o[3] = q3 + bc[3];
        o[4] = q4 + bc[4]; o[5] = q5 + bc[5]; o[6] = q6 + bc[6]; o[7] = q7 + bc[7];
    }
}

extern "C" void kernel_launch(void* const* d_in, const int* in_sizes, int n_in,
                              void* d_out, int out_size, void* d_ws, size_t ws_size,
                              hipStream_t stream) {
    (void)in_sizes; (void)n_in; (void)out_size; (void)ws_size;
    const float* feats = (const float*)d_in[0];
    const float* norm  = (const float*)d_in[1];
    const float* tao1L = (const float*)d_in[2];
    const float* tao2L = (const float*)d_in[3];
    const float* tao1G = (const float*)d_in[4];
    const float* tao2G = (const float*)d_in[5];
    const float* PPMI  = (const float*)d_in[6];
    const float* w1  = (const float*)d_in[7];
    const float* b1  = (const float*)d_in[8];
    const float* w2  = (const float*)d_in[9];
    const float* b2  = (const float*)d_in[10];
    const float* w1g = (const float*)d_in[11];
    const float* b1g = (const float*)d_in[12];
    const float* w2g = (const float*)d_in[13];
    const float* b2g = (const float*)d_in[14];
    const float* Wa  = (const float*)d_in[15];
    const float* Wc  = (const float*)d_in[16];
    const float* bc  = (const float*)d_in[17];
    const int* src = (const int*)d_in[18];
    const int* dst = (const int*)d_in[19];

    char* ws = (char*)d_ws;
    size_t off = 0;
    auto alloc = [&](size_t b) { void* p = (void*)(ws + off); off += (b + 255) & ~(size_t)255; return p; };
    unsigned short* ppmi_bf = (unsigned short*)alloc((size_t)NN * NN * 2);     // 134 MB
    unsigned short* fh = (unsigned short*)alloc((size_t)NN * DIN * 2);
    unsigned short* fl = (unsigned short*)alloc((size_t)NN * DIN * 2);
    unsigned short* w1lh = (unsigned short*)alloc((size_t)DH * DIN * 2);
    unsigned short* w1ll = (unsigned short*)alloc((size_t)DH * DIN * 2);
    unsigned short* w2lh = (unsigned short*)alloc((size_t)DO_ * DH * 2);
    unsigned short* w2ll = (unsigned short*)alloc((size_t)DO_ * DH * 2);
    unsigned short* w1gh = (unsigned short*)alloc((size_t)DH * DIN * 2);
    unsigned short* w1gl = (unsigned short*)alloc((size_t)DH * DIN * 2);
    unsigned short* w2gh = (unsigned short*)alloc((size_t)DO_ * DH * 2);
    unsigned short* w2gl = (unsigned short*)alloc((size_t)DO_ * DH * 2);
    unsigned short* g0t = (unsigned short*)alloc((size_t)DH * NN * 2);
    unsigned short* g2h = (unsigned short*)alloc((size_t)NN * DH * 2);
    unsigned short* g2l = (unsigned short*)alloc((size_t)NN * DH * 2);
    unsigned short* g3t = (unsigned short*)alloc((size_t)DO_ * NN * 2);
    unsigned short* h1h = (unsigned short*)alloc((size_t)NN * DH * 2);
    unsigned short* h1l = (unsigned short*)alloc((size_t)NN * DH * 2);
    float* HL  = (float*)alloc((size_t)NN * DO_ * 4);
    float* HG  = (float*)alloc((size_t)NN * DO_ * 4);
    // CSR arrays
    int* deg  = (int*)alloc((size_t)NN * 4);
    int* rs   = (int*)alloc((size_t)(NN + 1) * 4);
    int* cur  = (int*)alloc((size_t)NN * 4);
    int* csrc = (int*)alloc((size_t)NE * 4);
    // big region reused sequentially: local h0/h2 first, then split-K partials
    char* big = (char*)alloc((size_t)8 * NN * DO_ * 4);                        // 33.5 MB
    float* h0 = (float*)big;                         // NN*DH*4 = 8.4 MB
    float* h2 = (float*)(big + (size_t)NN * DH * 4); // NN*DO_*4 = 4.2 MB
    float* part = (float*)big;

    // CSR build (shared by both propagation layers)
    hipMemsetAsync(deg, 0, (size_t)NN * 4, stream);
    k_hist<<<dim3(NE / 256), dim3(256), 0, stream>>>(dst, deg);
    k_scan<<<dim3(1), dim3(1024), 0, stream>>>(deg, rs, cur);
    k_fill<<<dim3(NE / 256), dim3(256), 0, stream>>>(src, dst, cur, csrc);

    // conversions
    k_cvt_bf16<<<dim3(8192), dim3(256), 0, stream>>>(PPMI, ppmi_bf, NN * NN / 4);
    k_cvt_split<<<dim3(2048), dim3(256), 0, stream>>>(feats, fh, fl, NN * DIN / 4);

    // effective weights (split bf16, transposed)
    k_eff_split<<<dim3((DIN * DH + 255) / 256), dim3(256), 0, stream>>>(w1,  tao1L, w1lh, w1ll, DIN, DH, DH);
    k_eff_split<<<dim3((DH * DO_ + 255) / 256), dim3(256), 0, stream>>>(w2,  tao2L, w2lh, w2ll, DH, DO_, DO_);
    k_eff_split<<<dim3((DIN * DH + 255) / 256), dim3(256), 0, stream>>>(w1g, tao1G, w1gh, w1gl, DIN, DH, DH);
    k_eff_split<<<dim3((DH * DO_ + 255) / 256), dim3(256), 0, stream>>>(w2g, tao2G, w2gh, w2gl, DH, DO_, DO_);

    // ---- local branch (all ≈fp32 precision) ----
    k_gemm_split<0><<<dim3(64, 2), dim3(256), 0, stream>>>(fh, fl, w1lh, w1ll, h0, NN, DH, DIN);
    k_gather256<<<dim3(NN / 4), dim3(256), 0, stream>>>(h0, rs, csrc, norm, b1, h1h, h1l);
    k_gemm_split<0><<<dim3(64, 1), dim3(256), 0, stream>>>(h1h, h1l, w2lh, w2ll, h2, NN, DO_, DH);
    k_gather128<<<dim3(NN / 4), dim3(256), 0, stream>>>(h2, rs, csrc, norm, b2, HL);

    // ---- global branch (PPMI GEMMs single-bf16: results are O(0.01), err negligible) ----
    k_gemm_split<2><<<dim3(64, 2), dim3(256), 0, stream>>>(fh, fl, w1gh, w1gl, g0t, NN, DH, DIN);
    k_gemm_part<<<dim3(64, 2, 4), dim3(256), 0, stream>>>(ppmi_bf, g0t, part, NN, DH, NN, NN / 4);
    k_combine<1><<<dim3(NN * DH / 4 / 256), dim3(256), 0, stream>>>(part, g2h, g2l, b1g, NN, DH, 4);
    k_gemm_split<2><<<dim3(64, 1), dim3(256), 0, stream>>>(g2h, g2l, w2gh, w2gl, g3t, NN, DO_, DH);
    k_gemm_part<<<dim3(64, 1, 8), dim3(256), 0, stream>>>(ppmi_bf, g3t, part, NN, DO_, NN, NN / 8);
    k_combine<0><<<dim3(NN * DO_ / 4 / 256), dim3(256), 0, stream>>>(part, HG, nullptr, b2g, NN, DO_, 8);

    // ---- attention fusion + classifier ----
    k_attn<<<dim3(NN / 4), dim3(256), 0, stream>>>(HL, HG, Wa, Wc, bc, (float*)d_out);
}

// Round 4
// 673.066 us; speedup vs baseline: 2.8611x; 1.0445x over previous
//
#include <hip/hip_runtime.h>
#include <hip/hip_bf16.h>

#define NN 8192
#define DIN 512
#define DH 256
#define DO_ 128
#define NCLS 8
#define NE 262144

typedef __attribute__((ext_vector_type(8))) short bf16x8;
typedef __attribute__((ext_vector_type(4))) float f32x4;
typedef __attribute__((ext_vector_type(4))) unsigned short u16x4;

__device__ __forceinline__ unsigned short f2bf(float x) {
    unsigned int u = __float_as_uint(x);
    return (unsigned short)((u + 0x7FFFu + ((u >> 16) & 1u)) >> 16);
}
__device__ __forceinline__ float bf2f(unsigned short h) {
    return __uint_as_float((unsigned int)h << 16);
}

// ---------------- f32 -> bf16 convert (vectorized, grid-stride) ----------------
__global__ void k_cvt_bf16(const float* __restrict__ in, unsigned short* __restrict__ out, int n4) {
    int i = blockIdx.x * blockDim.x + threadIdx.x;
    int stride = gridDim.x * blockDim.x;
    for (; i < n4; i += stride) {
        float4 v = ((const float4*)in)[i];
        u16x4 o;
        o.x = f2bf(v.x); o.y = f2bf(v.y); o.z = f2bf(v.z); o.w = f2bf(v.w);
        ((u16x4*)out)[i] = o;
    }
}

// ---------- f32 -> split bf16 hi/lo (A = hi + lo, rel err ~2^-17) ----------
__global__ void k_cvt_split(const float* __restrict__ in, unsigned short* __restrict__ hi,
                            unsigned short* __restrict__ lo, int n4) {
    int i = blockIdx.x * blockDim.x + threadIdx.x;
    int stride = gridDim.x * blockDim.x;
    for (; i < n4; i += stride) {
        float4 v = ((const float4*)in)[i];
        u16x4 oh, ol;
        oh.x = f2bf(v.x); ol.x = f2bf(v.x - bf2f(oh.x));
        oh.y = f2bf(v.y); ol.y = f2bf(v.y - bf2f(oh.y));
        oh.z = f2bf(v.z); ol.z = f2bf(v.z - bf2f(oh.z));
        oh.w = f2bf(v.w); ol.w = f2bf(v.w - bf2f(oh.w));
        ((u16x4*)hi)[i] = oh;
        ((u16x4*)lo)[i] = ol;
    }
}

// -- effT[j][i] = sum_k w[i][k]*tao[k][j], stored as split bf16 hi/lo, transposed --
// Coalescing: consecutive lanes own consecutive j -> w load is wave-uniform
// broadcast (1 line), tao load is coalesced. (Was i-per-lane: 64 lines/load.)
__global__ void k_eff_split(const float* __restrict__ w, const float* __restrict__ tao,
                            unsigned short* __restrict__ effTh, unsigned short* __restrict__ effTl,
                            int I, int K0, int J) {
    int idx = blockIdx.x * blockDim.x + threadIdx.x;
    if (idx >= I * J) return;
    int j = idx % J, i = idx / J;
    float s = 0.f;
    for (int k = 0; k < K0; ++k) s += w[i * K0 + k] * tao[k * J + j];
    unsigned short h = f2bf(s);
    effTh[j * I + i] = h;
    effTl[j * I + i] = f2bf(s - bf2f(h));
}

#define GLDS(gp, lp) __builtin_amdgcn_global_load_lds( \
    (const __attribute__((address_space(1))) void*)(gp), \
    (__attribute__((address_space(3))) void*)(lp), 16, 0, 0)

// ---------------- single-bf16 MFMA GEMM, split-K partial out ----------------
__global__ __launch_bounds__(256) void k_gemm_part(
    const unsigned short* __restrict__ A, const unsigned short* __restrict__ B,
    float* __restrict__ C, int M, int N, int K, int kPerSplit)
{
    __shared__ unsigned short As[128 * 32];
    __shared__ unsigned short Bs[128 * 32];
    const int t = threadIdx.x;
    const int w = t >> 6;
    const int l = t & 63;
    const int wr = (w >> 1) * 64;
    const int wc = (w & 1) * 64;
    const long row0 = (long)blockIdx.x * 128;
    const long col0 = (long)blockIdx.y * 128;
    const long kbeg = (long)blockIdx.z * kPerSplit;
    const int nk = kPerSplit >> 5;

    f32x4 acc[4][4];
#pragma unroll
    for (int mi = 0; mi < 4; ++mi)
#pragma unroll
        for (int ni = 0; ni < 4; ++ni) {
            f32x4 z = {0.f, 0.f, 0.f, 0.f};
            acc[mi][ni] = z;
        }

    const int srow = (w << 4) + (l >> 2);
    const int skk  = (l & 3) << 3;
    const unsigned short* Abase = A + row0 * K + kbeg + skk;
    const unsigned short* Bbase = B + col0 * K + kbeg + skk;
    unsigned short* AsW = &As[w << 9];
    unsigned short* BsW = &Bs[w << 9];

    for (int kt = 0; kt < nk; ++kt) {
        const long ko = (long)kt << 5;
        __syncthreads();
        GLDS(Abase + (long)srow * K + ko,        AsW);
        GLDS(Abase + (long)(srow + 64) * K + ko, AsW + 2048);
        GLDS(Bbase + (long)srow * K + ko,        BsW);
        GLDS(Bbase + (long)(srow + 64) * K + ko, BsW + 2048);
        __syncthreads();

        const int ro  = (l & 15);
        const int kof = (l >> 4) << 3;
        bf16x8 a[4], b[4];
#pragma unroll
        for (int mi = 0; mi < 4; ++mi)
            a[mi] = *(const bf16x8*)&As[(wr + mi * 16 + ro) * 32 + kof];
#pragma unroll
        for (int ni = 0; ni < 4; ++ni)
            b[ni] = *(const bf16x8*)&Bs[(wc + ni * 16 + ro) * 32 + kof];
#pragma unroll
        for (int mi = 0; mi < 4; ++mi)
#pragma unroll
            for (int ni = 0; ni < 4; ++ni)
                acc[mi][ni] = __builtin_amdgcn_mfma_f32_16x16x32_bf16(a[mi], b[ni], acc[mi][ni], 0, 0, 0);
    }

    float* Cp = C + (long)blockIdx.z * M * N;
#pragma unroll
    for (int mi = 0; mi < 4; ++mi)
#pragma unroll
        for (int ni = 0; ni < 4; ++ni) {
            const long col = col0 + wc + ni * 16 + (l & 15);
            const long rbase = row0 + wr + mi * 16 + ((l >> 4) << 2);
            f32x4 v = acc[mi][ni];
#pragma unroll
            for (int j = 0; j < 4; ++j) Cp[(rbase + j) * N + col] = v[j];
        }
}

// ------------- split-bf16 3-term MFMA GEMM (≈fp32 precision) -------------
// C = (Ah+Al)@(Bh+Bl)^T dropping Al*Bl. OUT_MODE: 0 = f32 [M,N]; 2 = bf16 [N,M].
template<int OUT_MODE>
__global__ __launch_bounds__(256) void k_gemm_split(
    const unsigned short* __restrict__ Ah, const unsigned short* __restrict__ Al,
    const unsigned short* __restrict__ Bh, const unsigned short* __restrict__ Bl,
    void* __restrict__ C, int M, int N, int K)
{
    __shared__ unsigned short AsH[128 * 32];
    __shared__ unsigned short AsL[128 * 32];
    __shared__ unsigned short BsH[128 * 32];
    __shared__ unsigned short BsL[128 * 32];
    const int t = threadIdx.x;
    const int w = t >> 6;
    const int l = t & 63;
    const int wr = (w >> 1) * 64;
    const int wc = (w & 1) * 64;
    const long row0 = (long)blockIdx.x * 128;
    const long col0 = (long)blockIdx.y * 128;
    const int nk = K >> 5;

    f32x4 acc[4][4];
#pragma unroll
    for (int mi = 0; mi < 4; ++mi)
#pragma unroll
        for (int ni = 0; ni < 4; ++ni) {
            f32x4 z = {0.f, 0.f, 0.f, 0.f};
            acc[mi][ni] = z;
        }

    const int srow = (w << 4) + (l >> 2);
    const int skk  = (l & 3) << 3;
    const long aoff = row0 * K + skk;
    const long boff = col0 * K + skk;
    unsigned short* AsHW = &AsH[w << 9];
    unsigned short* AsLW = &AsL[w << 9];
    unsigned short* BsHW = &BsH[w << 9];
    unsigned short* BsLW = &BsL[w << 9];

    for (int kt = 0; kt < nk; ++kt) {
        const long ko = (long)kt << 5;
        __syncthreads();
        GLDS(Ah + aoff + (long)srow * K + ko,        AsHW);
        GLDS(Ah + aoff + (long)(srow + 64) * K + ko, AsHW + 2048);
        GLDS(Al + aoff + (long)srow * K + ko,        AsLW);
        GLDS(Al + aoff + (long)(srow + 64) * K + ko, AsLW + 2048);
        GLDS(Bh + boff + (long)srow * K + ko,        BsHW);
        GLDS(Bh + boff + (long)(srow + 64) * K + ko, BsHW + 2048);
        GLDS(Bl + boff + (long)srow * K + ko,        BsLW);
        GLDS(Bl + boff + (long)(srow + 64) * K + ko, BsLW + 2048);
        __syncthreads();

        const int ro  = (l & 15);
        const int kof = (l >> 4) << 3;
        bf16x8 ah[4], al[4], bh[4], bl[4];
#pragma unroll
        for (int mi = 0; mi < 4; ++mi) {
            ah[mi] = *(const bf16x8*)&AsH[(wr + mi * 16 + ro) * 32 + kof];
            al[mi] = *(const bf16x8*)&AsL[(wr + mi * 16 + ro) * 32 + kof];
        }
#pragma unroll
        for (int ni = 0; ni < 4; ++ni) {
            bh[ni] = *(const bf16x8*)&BsH[(wc + ni * 16 + ro) * 32 + kof];
            bl[ni] = *(const bf16x8*)&BsL[(wc + ni * 16 + ro) * 32 + kof];
        }
#pragma unroll
        for (int mi = 0; mi < 4; ++mi)
#pragma unroll
            for (int ni = 0; ni < 4; ++ni) {
                acc[mi][ni] = __builtin_amdgcn_mfma_f32_16x16x32_bf16(ah[mi], bl[ni], acc[mi][ni], 0, 0, 0);
                acc[mi][ni] = __builtin_amdgcn_mfma_f32_16x16x32_bf16(al[mi], bh[ni], acc[mi][ni], 0, 0, 0);
                acc[mi][ni] = __builtin_amdgcn_mfma_f32_16x16x32_bf16(ah[mi], bh[ni], acc[mi][ni], 0, 0, 0);
            }
    }

#pragma unroll
    for (int mi = 0; mi < 4; ++mi)
#pragma unroll
        for (int ni = 0; ni < 4; ++ni) {
            const long col = col0 + wc + ni * 16 + (l & 15);
            const long rbase = row0 + wr + mi * 16 + ((l >> 4) << 2);
            f32x4 v = acc[mi][ni];
            if (OUT_MODE == 0) {
                float* Cp = (float*)C;
#pragma unroll
                for (int j = 0; j < 4; ++j) Cp[(rbase + j) * N + col] = v[j];
            } else {
                u16x4 o;
                o.x = f2bf(v[0]); o.y = f2bf(v[1]); o.z = f2bf(v[2]); o.w = f2bf(v[3]);
                *(u16x4*)((unsigned short*)C + col * M + rbase) = o;
            }
        }
}

// ------------- split-K combine: sum partials, +bias, relu -------------
// OM: 0 = f32 out; 1 = split bf16 hi/lo out
template<int OM>
__global__ void k_combine(const float* __restrict__ part, void* __restrict__ out,
                          void* __restrict__ out2, const float* __restrict__ bias,
                          int M, int N, int Z) {
    int idx = blockIdx.x * blockDim.x + threadIdx.x;
    int n4 = N >> 2;
    if (idx >= M * n4) return;
    int m = idx / n4, c = idx % n4;
    float4 s = make_float4(0.f, 0.f, 0.f, 0.f);
    for (int z = 0; z < Z; ++z) {
        float4 p = *(const float4*)&part[((long)z * M + m) * N + (c << 2)];
        s.x += p.x; s.y += p.y; s.z += p.z; s.w += p.w;
    }
    float4 b = *(const float4*)&bias[c << 2];
    s.x = fmaxf(s.x + b.x, 0.f);
    s.y = fmaxf(s.y + b.y, 0.f);
    s.z = fmaxf(s.z + b.z, 0.f);
    s.w = fmaxf(s.w + b.w, 0.f);
    if (OM == 0) {
        *(float4*)((float*)out + (long)m * N + (c << 2)) = s;
    } else {
        u16x4 oh, ol;
        oh.x = f2bf(s.x); ol.x = f2bf(s.x - bf2f(oh.x));
        oh.y = f2bf(s.y); ol.y = f2bf(s.y - bf2f(oh.y));
        oh.z = f2bf(s.z); ol.z = f2bf(s.z - bf2f(oh.z));
        oh.w = f2bf(s.w); ol.w = f2bf(s.w - bf2f(oh.w));
        *(u16x4*)((unsigned short*)out  + (long)m * N + (c << 2)) = oh;
        *(u16x4*)((unsigned short*)out2 + (long)m * N + (c << 2)) = ol;
    }
}

// ================= CSR build: histogram -> scan -> fill =================
__global__ void k_hist(const int* __restrict__ dstv, int* __restrict__ deg) {
    int e = blockIdx.x * blockDim.x + threadIdx.x;
    if (e < NE) atomicAdd(&deg[dstv[e]], 1);
}

// single block of 1024 threads, exclusive scan of 8192 degrees
__global__ __launch_bounds__(1024) void k_scan(const int* __restrict__ deg,
                                               int* __restrict__ rs, int* __restrict__ cur) {
    __shared__ int sums[1024];
    int t = threadIdx.x;
    int loc[8];
    int s = 0;
#pragma unroll
    for (int j = 0; j < 8; ++j) { loc[j] = deg[t * 8 + j]; s += loc[j]; }
    sums[t] = s;
    __syncthreads();
    for (int off = 1; off < 1024; off <<= 1) {
        int v = (t >= off) ? sums[t - off] : 0;
        __syncthreads();
        sums[t] += v;
        __syncthreads();
    }
    int base = (t > 0) ? sums[t - 1] : 0;
#pragma unroll
    for (int j = 0; j < 8; ++j) {
        rs[t * 8 + j] = base;
        cur[t * 8 + j] = base;
        base += loc[j];
    }
    if (t == 1023) rs[8192] = base;
}

__global__ void k_fill(const int* __restrict__ srcv, const int* __restrict__ dstv,
                       int* __restrict__ cur, int* __restrict__ csrc) {
    int e = blockIdx.x * blockDim.x + threadIdx.x;
    if (e >= NE) return;
    int pos = atomicAdd(&cur[dstv[e]], 1);
    csrc[pos] = srcv[e];
}

// ====== CSR gather prop, D=256: wave per dst row, lane owns float4 column ======
__global__ __launch_bounds__(256) void k_gather256(
    const float* __restrict__ h, const int* __restrict__ rs, const int* __restrict__ csrc,
    const float* __restrict__ norm, const float* __restrict__ bias,
    unsigned short* __restrict__ outh, unsigned short* __restrict__ outl) {
    int wv = threadIdx.x >> 6, l = threadIdx.x & 63;
    int row = blockIdx.x * 4 + wv;
    int beg = rs[row], end = rs[row + 1];
    float4 acc = make_float4(0.f, 0.f, 0.f, 0.f);
    for (int i = beg; i < end; ++i) {
        int s = csrc[i];
        float ns = norm[s];
        float4 hv = *(const float4*)&h[((long)s << 8) + (l << 2)];
        acc.x += hv.x * ns; acc.y += hv.y * ns; acc.z += hv.z * ns; acc.w += hv.w * ns;
    }
    float nv = norm[row];
    float4 b = *(const float4*)&bias[l << 2];
    float4 r;
    r.x = fmaxf(acc.x * nv + b.x, 0.f);
    r.y = fmaxf(acc.y * nv + b.y, 0.f);
    r.z = fmaxf(acc.z * nv + b.z, 0.f);
    r.w = fmaxf(acc.w * nv + b.w, 0.f);
    u16x4 oh, ol;
    oh.x = f2bf(r.x); ol.x = f2bf(r.x - bf2f(oh.x));
    oh.y = f2bf(r.y); ol.y = f2bf(r.y - bf2f(oh.y));
    oh.z = f2bf(r.z); ol.z = f2bf(r.z - bf2f(oh.z));
    oh.w = f2bf(r.w); ol.w = f2bf(r.w - bf2f(oh.w));
    *(u16x4*)&outh[((long)row << 8) + (l << 2)] = oh;
    *(u16x4*)&outl[((long)row << 8) + (l << 2)] = ol;
}

// ====== CSR gather prop, D=128: wave per dst row, lane owns float2 column ======
__global__ __launch_bounds__(256) void k_gather128(
    const float* __restrict__ h, const int* __restrict__ rs, const int* __restrict__ csrc,
    const float* __restrict__ norm, const float* __restrict__ bias,
    float* __restrict__ out) {
    int wv = threadIdx.x >> 6, l = threadIdx.x & 63;
    int row = blockIdx.x * 4 + wv;
    int beg = rs[row], end = rs[row + 1];
    float2 acc = make_float2(0.f, 0.f);
    for (int i = beg; i < end; ++i) {
        int s = csrc[i];
        float ns = norm[s];
        float2 hv = *(const float2*)&h[((long)s << 7) + (l << 1)];
        acc.x += hv.x * ns; acc.y += hv.y * ns;
    }
    float nv = norm[row];
    float2 b = *(const float2*)&bias[l << 1];
    float2 r;
    r.x = fmaxf(acc.x * nv + b.x, 0.f);
    r.y = fmaxf(acc.y * nv + b.y, 0.f);
    *(float2*)&out[((long)row << 7) + (l << 1)] = r;
}

// ------------- attention fusion + classifier (one wave per row) -------------
__global__ __launch_bounds__(256) void k_attn(
    const float* __restrict__ HL, const float* __restrict__ HG,
    const float* __restrict__ Wa, const float* __restrict__ Wc,
    const float* __restrict__ bc, float* __restrict__ out) {
    int wv = threadIdx.x >> 6, l = threadIdx.x & 63;
    int row = blockIdx.x * 4 + wv;
    float2 hl = *(const float2*)&HL[(long)row * DO_ + l * 2];
    float2 hg = *(const float2*)&HG[(long)row * DO_ + l * 2];
    float4 wa0 = *(const float4*)&Wa[(2 * l) * 2];
    float4 wa1 = *(const float4*)&Wa[(DO_ + 2 * l) * 2];
    float p0 = hl.x * wa0.x + hl.y * wa0.z + hg.x * wa1.x + hg.y * wa1.z;
    float p1 = hl.x * wa0.y + hl.y * wa0.w + hg.x * wa1.y + hg.y * wa1.w;
#pragma unroll
    for (int off = 32; off >= 1; off >>= 1) {
        p0 += __shfl_xor(p0, off);
        p1 += __shfl_xor(p1, off);
    }
    float mx = fmaxf(p0, p1);
    float e0 = __expf(p0 - mx), e1 = __expf(p1 - mx);
    float inv = 1.f / (e0 + e1);
    float a0 = e0 * inv, a1 = e1 * inv;
    float z0 = a0 * hl.x + a1 * hg.x;
    float z1 = a0 * hl.y + a1 * hg.y;
    float4 wcA0 = *(const float4*)&Wc[(2 * l) * NCLS];
    float4 wcA1 = *(const float4*)&Wc[(2 * l) * NCLS + 4];
    float4 wcB0 = *(const float4*)&Wc[(2 * l + 1) * NCLS];
    float4 wcB1 = *(const float4*)&Wc[(2 * l + 1) * NCLS + 4];
    float q0 = z0 * wcA0.x + z1 * wcB0.x;
    float q1 = z0 * wcA0.y + z1 * wcB0.y;
    float q2 = z0 * wcA0.z + z1 * wcB0.z;
    float q3 = z0 * wcA0.w + z1 * wcB0.w;
    float q4 = z0 * wcA1.x + z1 * wcB1.x;
    float q5 = z0 * wcA1.y + z1 * wcB1.y;
    float q6 = z0 * wcA1.z + z1 * wcB1.z;
    float q7 = z0 * wcA1.w + z1 * wcB1.w;
#pragma unroll
    for (int off = 32; off >= 1; off >>= 1) {
        q0 += __shfl_xor(q0, off); q1 += __shfl_xor(q1, off);
        q2 += __shfl_xor(q2, off); q3 += __shfl_xor(q3, off);
        q4 += __shfl_xor(q4, off); q5 += __shfl_xor(q5, off);
        q6 += __shfl_xor(q6, off); q7 += __shfl_xor(q7, off);
    }
    if (l == 0) {
        float* o = &out[(long)row * NCLS];
        o[0] = q0 + bc[0]; o[1] = q1 + bc[1]; o[2] = q2 + bc[2]; o[3] = q3 + bc[3];
        o[4] = q4 + bc[4]; o[5] = q5 + bc[5]; o[6] = q6 + bc[6]; o[7] = q7 + bc[7];
    }
}

extern "C" void kernel_launch(void* const* d_in, const int* in_sizes, int n_in,
                              void* d_out, int out_size, void* d_ws, size_t ws_size,
                              hipStream_t stream) {
    (void)in_sizes; (void)n_in; (void)out_size; (void)ws_size;
    const float* feats = (const float*)d_in[0];
    const float* norm  = (const float*)d_in[1];
    const float* tao1L = (const float*)d_in[2];
    const float* tao2L = (const float*)d_in[3];
    const float* tao1G = (const float*)d_in[4];
    const float* tao2G = (const float*)d_in[5];
    const float* PPMI  = (const float*)d_in[6];
    const float* w1  = (const float*)d_in[7];
    const float* b1  = (const float*)d_in[8];
    const float* w2  = (const float*)d_in[9];
    const float* b2  = (const float*)d_in[10];
    const float* w1g = (const float*)d_in[11];
    const float* b1g = (const float*)d_in[12];
    const float* w2g = (const float*)d_in[13];
    const float* b2g = (const float*)d_in[14];
    const float* Wa  = (const float*)d_in[15];
    const float* Wc  = (const float*)d_in[16];
    const float* bc  = (const float*)d_in[17];
    const int* src = (const int*)d_in[18];
    const int* dst = (const int*)d_in[19];

    char* ws = (char*)d_ws;
    size_t off = 0;
    auto alloc = [&](size_t b) { void* p = (void*)(ws + off); off += (b + 255) & ~(size_t)255; return p; };
    unsigned short* ppmi_bf = (unsigned short*)alloc((size_t)NN * NN * 2);     // 134 MB
    unsigned short* fh = (unsigned short*)alloc((size_t)NN * DIN * 2);
    unsigned short* fl = (unsigned short*)alloc((size_t)NN * DIN * 2);
    unsigned short* w1lh = (unsigned short*)alloc((size_t)DH * DIN * 2);
    unsigned short* w1ll = (unsigned short*)alloc((size_t)DH * DIN * 2);
    unsigned short* w2lh = (unsigned short*)alloc((size_t)DO_ * DH * 2);
    unsigned short* w2ll = (unsigned short*)alloc((size_t)DO_ * DH * 2);
    unsigned short* w1gh = (unsigned short*)alloc((size_t)DH * DIN * 2);
    unsigned short* w1gl = (unsigned short*)alloc((size_t)DH * DIN * 2);
    unsigned short* w2gh = (unsigned short*)alloc((size_t)DO_ * DH * 2);
    unsigned short* w2gl = (unsigned short*)alloc((size_t)DO_ * DH * 2);
    unsigned short* g0t = (unsigned short*)alloc((size_t)DH * NN * 2);
    unsigned short* g2h = (unsigned short*)alloc((size_t)NN * DH * 2);
    unsigned short* g2l = (unsigned short*)alloc((size_t)NN * DH * 2);
    unsigned short* g3t = (unsigned short*)alloc((size_t)DO_ * NN * 2);
    unsigned short* h1h = (unsigned short*)alloc((size_t)NN * DH * 2);
    unsigned short* h1l = (unsigned short*)alloc((size_t)NN * DH * 2);
    float* HL  = (float*)alloc((size_t)NN * DO_ * 4);
    float* HG  = (float*)alloc((size_t)NN * DO_ * 4);
    // CSR arrays
    int* deg  = (int*)alloc((size_t)NN * 4);
    int* rs   = (int*)alloc((size_t)(NN + 1) * 4);
    int* cur  = (int*)alloc((size_t)NN * 4);
    int* csrc = (int*)alloc((size_t)NE * 4);
    // big region reused sequentially: local h0/h2 first, then split-K partials
    char* big = (char*)alloc((size_t)8 * NN * DO_ * 4);                        // 33.5 MB
    float* h0 = (float*)big;                         // NN*DH*4 = 8.4 MB
    float* h2 = (float*)(big + (size_t)NN * DH * 4); // NN*DO_*4 = 4.2 MB
    float* part = (float*)big;

    // CSR build (shared by both propagation layers)
    hipMemsetAsync(deg, 0, (size_t)NN * 4, stream);
    k_hist<<<dim3(NE / 256), dim3(256), 0, stream>>>(dst, deg);
    k_scan<<<dim3(1), dim3(1024), 0, stream>>>(deg, rs, cur);
    k_fill<<<dim3(NE / 256), dim3(256), 0, stream>>>(src, dst, cur, csrc);

    // conversions
    k_cvt_bf16<<<dim3(8192), dim3(256), 0, stream>>>(PPMI, ppmi_bf, NN * NN / 4);
    k_cvt_split<<<dim3(2048), dim3(256), 0, stream>>>(feats, fh, fl, NN * DIN / 4);

    // effective weights (split bf16, transposed)
    k_eff_split<<<dim3((DIN * DH + 255) / 256), dim3(256), 0, stream>>>(w1,  tao1L, w1lh, w1ll, DIN, DH, DH);
    k_eff_split<<<dim3((DH * DO_ + 255) / 256), dim3(256), 0, stream>>>(w2,  tao2L, w2lh, w2ll, DH, DO_, DO_);
    k_eff_split<<<dim3((DIN * DH + 255) / 256), dim3(256), 0, stream>>>(w1g, tao1G, w1gh, w1gl, DIN, DH, DH);
    k_eff_split<<<dim3((DH * DO_ + 255) / 256), dim3(256), 0, stream>>>(w2g, tao2G, w2gh, w2gl, DH, DO_, DO_);

    // ---- local branch (all ≈fp32 precision) ----
    k_gemm_split<0><<<dim3(64, 2), dim3(256), 0, stream>>>(fh, fl, w1lh, w1ll, h0, NN, DH, DIN);
    k_gather256<<<dim3(NN / 4), dim3(256), 0, stream>>>(h0, rs, csrc, norm, b1, h1h, h1l);
    k_gemm_split<0><<<dim3(64, 1), dim3(256), 0, stream>>>(h1h, h1l, w2lh, w2ll, h2, NN, DO_, DH);
    k_gather128<<<dim3(NN / 4), dim3(256), 0, stream>>>(h2, rs, csrc, norm, b2, HL);

    // ---- global branch (PPMI GEMMs single-bf16: results are O(0.01), err negligible) ----
    k_gemm_split<2><<<dim3(64, 2), dim3(256), 0, stream>>>(fh, fl, w1gh, w1gl, g0t, NN, DH, DIN);
    k_gemm_part<<<dim3(64, 2, 4), dim3(256), 0, stream>>>(ppmi_bf, g0t, part, NN, DH, NN, NN / 4);
    k_combine<1><<<dim3(NN * DH / 4 / 256), dim3(256), 0, stream>>>(part, g2h, g2l, b1g, NN, DH, 4);
    k_gemm_split<2><<<dim3(64, 1), dim3(256), 0, stream>>>(g2h, g2l, w2gh, w2gl, g3t, NN, DO_, DH);
    k_gemm_part<<<dim3(64, 1, 8), dim3(256), 0, stream>>>(ppmi_bf, g3t, part, NN, DO_, NN, NN / 8);
    k_combine<0><<<dim3(NN * DO_ / 4 / 256), dim3(256), 0, stream>>>(part, HG, nullptr, b2g, NN, DO_, 8);

    // ---- attention fusion + classifier ----
    k_attn<<<dim3(NN / 4), dim3(256), 0, stream>>>(HL, HG, Wa, Wc, bc, (float*)d_out);
}

// Round 5
// 664.446 us; speedup vs baseline: 2.8982x; 1.0130x over previous
//
#include <hip/hip_runtime.h>
#include <hip/hip_bf16.h>

#define NN 8192
#define DIN 512
#define DH 256
#define DO_ 128
#define NCLS 8
#define NE 262144

typedef __attribute__((ext_vector_type(8))) short bf16x8;
typedef __attribute__((ext_vector_type(4))) float f32x4;
typedef __attribute__((ext_vector_type(4))) unsigned short u16x4;

__device__ __forceinline__ unsigned short f2bf(float x) {
    unsigned int u = __float_as_uint(x);
    return (unsigned short)((u + 0x7FFFu + ((u >> 16) & 1u)) >> 16);
}
__device__ __forceinline__ float bf2f(unsigned short h) {
    return __uint_as_float((unsigned int)h << 16);
}

// ---------------- f32 -> bf16 convert (vectorized, grid-stride) ----------------
__global__ void k_cvt_bf16(const float* __restrict__ in, unsigned short* __restrict__ out, int n4) {
    int i = blockIdx.x * blockDim.x + threadIdx.x;
    int stride = gridDim.x * blockDim.x;
    for (; i < n4; i += stride) {
        float4 v = ((const float4*)in)[i];
        u16x4 o;
        o.x = f2bf(v.x); o.y = f2bf(v.y); o.z = f2bf(v.z); o.w = f2bf(v.w);
        ((u16x4*)out)[i] = o;
    }
}

// ---------- f32 -> split bf16 hi/lo (A = hi + lo, rel err ~2^-17) ----------
__global__ void k_cvt_split(const float* __restrict__ in, unsigned short* __restrict__ hi,
                            unsigned short* __restrict__ lo, int n4) {
    int i = blockIdx.x * blockDim.x + threadIdx.x;
    int stride = gridDim.x * blockDim.x;
    for (; i < n4; i += stride) {
        float4 v = ((const float4*)in)[i];
        u16x4 oh, ol;
        oh.x = f2bf(v.x); ol.x = f2bf(v.x - bf2f(oh.x));
        oh.y = f2bf(v.y); ol.y = f2bf(v.y - bf2f(oh.y));
        oh.z = f2bf(v.z); ol.z = f2bf(v.z - bf2f(oh.z));
        oh.w = f2bf(v.w); ol.w = f2bf(v.w - bf2f(oh.w));
        ((u16x4*)hi)[i] = oh;
        ((u16x4*)lo)[i] = ol;
    }
}

// -- effT[j][i] = sum_k w[i][k]*tao[k][j], stored as split bf16 hi/lo, transposed --
__global__ void k_eff_split(const float* __restrict__ w, const float* __restrict__ tao,
                            unsigned short* __restrict__ effTh, unsigned short* __restrict__ effTl,
                            int I, int K0, int J) {
    int idx = blockIdx.x * blockDim.x + threadIdx.x;
    if (idx >= I * J) return;
    int j = idx % J, i = idx / J;
    float s = 0.f;
    for (int k = 0; k < K0; ++k) s += w[i * K0 + k] * tao[k * J + j];
    unsigned short h = f2bf(s);
    effTh[j * I + i] = h;
    effTl[j * I + i] = f2bf(s - bf2f(h));
}

#define GLDS(gp, lp) __builtin_amdgcn_global_load_lds( \
    (const __attribute__((address_space(1))) void*)(gp), \
    (__attribute__((address_space(3))) void*)(lp), 16, 0, 0)

// ---------------- single-bf16 MFMA GEMM, split-K partial out ----------------
__global__ __launch_bounds__(256) void k_gemm_part(
    const unsigned short* __restrict__ A, const unsigned short* __restrict__ B,
    float* __restrict__ C, int M, int N, int K, int kPerSplit)
{
    __shared__ unsigned short As[128 * 32];
    __shared__ unsigned short Bs[128 * 32];
    const int t = threadIdx.x;
    const int w = t >> 6;
    const int l = t & 63;
    const int wr = (w >> 1) * 64;
    const int wc = (w & 1) * 64;
    const long row0 = (long)blockIdx.x * 128;
    const long col0 = (long)blockIdx.y * 128;
    const long kbeg = (long)blockIdx.z * kPerSplit;
    const int nk = kPerSplit >> 5;

    f32x4 acc[4][4];
#pragma unroll
    for (int mi = 0; mi < 4; ++mi)
#pragma unroll
        for (int ni = 0; ni < 4; ++ni) {
            f32x4 z = {0.f, 0.f, 0.f, 0.f};
            acc[mi][ni] = z;
        }

    const int srow = (w << 4) + (l >> 2);
    const int skk  = (l & 3) << 3;
    const unsigned short* Abase = A + row0 * K + kbeg + skk;
    const unsigned short* Bbase = B + col0 * K + kbeg + skk;
    unsigned short* AsW = &As[w << 9];
    unsigned short* BsW = &Bs[w << 9];

    for (int kt = 0; kt < nk; ++kt) {
        const long ko = (long)kt << 5;
        __syncthreads();
        GLDS(Abase + (long)srow * K + ko,        AsW);
        GLDS(Abase + (long)(srow + 64) * K + ko, AsW + 2048);
        GLDS(Bbase + (long)srow * K + ko,        BsW);
        GLDS(Bbase + (long)(srow + 64) * K + ko, BsW + 2048);
        __syncthreads();

        const int ro  = (l & 15);
        const int kof = (l >> 4) << 3;
        bf16x8 a[4], b[4];
#pragma unroll
        for (int mi = 0; mi < 4; ++mi)
            a[mi] = *(const bf16x8*)&As[(wr + mi * 16 + ro) * 32 + kof];
#pragma unroll
        for (int ni = 0; ni < 4; ++ni)
            b[ni] = *(const bf16x8*)&Bs[(wc + ni * 16 + ro) * 32 + kof];
#pragma unroll
        for (int mi = 0; mi < 4; ++mi)
#pragma unroll
            for (int ni = 0; ni < 4; ++ni)
                acc[mi][ni] = __builtin_amdgcn_mfma_f32_16x16x32_bf16(a[mi], b[ni], acc[mi][ni], 0, 0, 0);
    }

    float* Cp = C + (long)blockIdx.z * M * N;
#pragma unroll
    for (int mi = 0; mi < 4; ++mi)
#pragma unroll
        for (int ni = 0; ni < 4; ++ni) {
            const long col = col0 + wc + ni * 16 + (l & 15);
            const long rbase = row0 + wr + mi * 16 + ((l >> 4) << 2);
            f32x4 v = acc[mi][ni];
#pragma unroll
            for (int j = 0; j < 4; ++j) Cp[(rbase + j) * N + col] = v[j];
        }
}

// ------------- split-bf16 3-term MFMA GEMM (≈fp32 precision) -------------
// C = (Ah+Al)@(Bh+Bl)^T dropping Al*Bl. OUT_MODE: 0 = f32 [M,N]; 2 = bf16 [N,M].
template<int OUT_MODE>
__global__ __launch_bounds__(256) void k_gemm_split(
    const unsigned short* __restrict__ Ah, const unsigned short* __restrict__ Al,
    const unsigned short* __restrict__ Bh, const unsigned short* __restrict__ Bl,
    void* __restrict__ C, int M, int N, int K)
{
    __shared__ unsigned short AsH[128 * 32];
    __shared__ unsigned short AsL[128 * 32];
    __shared__ unsigned short BsH[128 * 32];
    __shared__ unsigned short BsL[128 * 32];
    const int t = threadIdx.x;
    const int w = t >> 6;
    const int l = t & 63;
    const int wr = (w >> 1) * 64;
    const int wc = (w & 1) * 64;
    const long row0 = (long)blockIdx.x * 128;
    const long col0 = (long)blockIdx.y * 128;
    const int nk = K >> 5;

    f32x4 acc[4][4];
#pragma unroll
    for (int mi = 0; mi < 4; ++mi)
#pragma unroll
        for (int ni = 0; ni < 4; ++ni) {
            f32x4 z = {0.f, 0.f, 0.f, 0.f};
            acc[mi][ni] = z;
        }

    const int srow = (w << 4) + (l >> 2);
    const int skk  = (l & 3) << 3;
    const long aoff = row0 * K + skk;
    const long boff = col0 * K + skk;
    unsigned short* AsHW = &AsH[w << 9];
    unsigned short* AsLW = &AsL[w << 9];
    unsigned short* BsHW = &BsH[w << 9];
    unsigned short* BsLW = &BsL[w << 9];

    for (int kt = 0; kt < nk; ++kt) {
        const long ko = (long)kt << 5;
        __syncthreads();
        GLDS(Ah + aoff + (long)srow * K + ko,        AsHW);
        GLDS(Ah + aoff + (long)(srow + 64) * K + ko, AsHW + 2048);
        GLDS(Al + aoff + (long)srow * K + ko,        AsLW);
        GLDS(Al + aoff + (long)(srow + 64) * K + ko, AsLW + 2048);
        GLDS(Bh + boff + (long)srow * K + ko,        BsHW);
        GLDS(Bh + boff + (long)(srow + 64) * K + ko, BsHW + 2048);
        GLDS(Bl + boff + (long)srow * K + ko,        BsLW);
        GLDS(Bl + boff + (long)(srow + 64) * K + ko, BsLW + 2048);
        __syncthreads();

        const int ro  = (l & 15);
        const int kof = (l >> 4) << 3;
        bf16x8 ah[4], al[4], bh[4], bl[4];
#pragma unroll
        for (int mi = 0; mi < 4; ++mi) {
            ah[mi] = *(const bf16x8*)&AsH[(wr + mi * 16 + ro) * 32 + kof];
            al[mi] = *(const bf16x8*)&AsL[(wr + mi * 16 + ro) * 32 + kof];
        }
#pragma unroll
        for (int ni = 0; ni < 4; ++ni) {
            bh[ni] = *(const bf16x8*)&BsH[(wc + ni * 16 + ro) * 32 + kof];
            bl[ni] = *(const bf16x8*)&BsL[(wc + ni * 16 + ro) * 32 + kof];
        }
#pragma unroll
        for (int mi = 0; mi < 4; ++mi)
#pragma unroll
            for (int ni = 0; ni < 4; ++ni) {
                acc[mi][ni] = __builtin_amdgcn_mfma_f32_16x16x32_bf16(ah[mi], bl[ni], acc[mi][ni], 0, 0, 0);
                acc[mi][ni] = __builtin_amdgcn_mfma_f32_16x16x32_bf16(al[mi], bh[ni], acc[mi][ni], 0, 0, 0);
                acc[mi][ni] = __builtin_amdgcn_mfma_f32_16x16x32_bf16(ah[mi], bh[ni], acc[mi][ni], 0, 0, 0);
            }
    }

#pragma unroll
    for (int mi = 0; mi < 4; ++mi)
#pragma unroll
        for (int ni = 0; ni < 4; ++ni) {
            const long col = col0 + wc + ni * 16 + (l & 15);
            const long rbase = row0 + wr + mi * 16 + ((l >> 4) << 2);
            f32x4 v = acc[mi][ni];
            if (OUT_MODE == 0) {
                float* Cp = (float*)C;
#pragma unroll
                for (int j = 0; j < 4; ++j) Cp[(rbase + j) * N + col] = v[j];
            } else {
                u16x4 o;
                o.x = f2bf(v[0]); o.y = f2bf(v[1]); o.z = f2bf(v[2]); o.w = f2bf(v[3]);
                *(u16x4*)((unsigned short*)C + col * M + rbase) = o;
            }
        }
}

// ------------- split-K combine: sum partials, +bias, relu -------------
template<int OM>
__global__ void k_combine(const float* __restrict__ part, void* __restrict__ out,
                          void* __restrict__ out2, const float* __restrict__ bias,
                          int M, int N, int Z) {
    int idx = blockIdx.x * blockDim.x + threadIdx.x;
    int n4 = N >> 2;
    if (idx >= M * n4) return;
    int m = idx / n4, c = idx % n4;
    float4 s = make_float4(0.f, 0.f, 0.f, 0.f);
    for (int z = 0; z < Z; ++z) {
        float4 p = *(const float4*)&part[((long)z * M + m) * N + (c << 2)];
        s.x += p.x; s.y += p.y; s.z += p.z; s.w += p.w;
    }
    float4 b = *(const float4*)&bias[c << 2];
    s.x = fmaxf(s.x + b.x, 0.f);
    s.y = fmaxf(s.y + b.y, 0.f);
    s.z = fmaxf(s.z + b.z, 0.f);
    s.w = fmaxf(s.w + b.w, 0.f);
    if (OM == 0) {
        *(float4*)((float*)out + (long)m * N + (c << 2)) = s;
    } else {
        u16x4 oh, ol;
        oh.x = f2bf(s.x); ol.x = f2bf(s.x - bf2f(oh.x));
        oh.y = f2bf(s.y); ol.y = f2bf(s.y - bf2f(oh.y));
        oh.z = f2bf(s.z); ol.z = f2bf(s.z - bf2f(oh.z));
        oh.w = f2bf(s.w); ol.w = f2bf(s.w - bf2f(oh.w));
        *(u16x4*)((unsigned short*)out  + (long)m * N + (c << 2)) = oh;
        *(u16x4*)((unsigned short*)out2 + (long)m * N + (c << 2)) = ol;
    }
}

// ================= CSR build: histogram -> scan -> fill =================
__global__ void k_hist(const int* __restrict__ dstv, int* __restrict__ deg) {
    int e = blockIdx.x * blockDim.x + threadIdx.x;
    if (e < NE) atomicAdd(&deg[dstv[e]], 1);
}

__global__ __launch_bounds__(1024) void k_scan(const int* __restrict__ deg,
                                               int* __restrict__ rs, int* __restrict__ cur) {
    __shared__ int sums[1024];
    int t = threadIdx.x;
    int loc[8];
    int s = 0;
#pragma unroll
    for (int j = 0; j < 8; ++j) { loc[j] = deg[t * 8 + j]; s += loc[j]; }
    sums[t] = s;
    __syncthreads();
    for (int off = 1; off < 1024; off <<= 1) {
        int v = (t >= off) ? sums[t - off] : 0;
        __syncthreads();
        sums[t] += v;
        __syncthreads();
    }
    int base = (t > 0) ? sums[t - 1] : 0;
#pragma unroll
    for (int j = 0; j < 8; ++j) {
        rs[t * 8 + j] = base;
        cur[t * 8 + j] = base;
        base += loc[j];
    }
    if (t == 1023) rs[8192] = base;
}

__global__ void k_fill(const int* __restrict__ srcv, const int* __restrict__ dstv,
                       int* __restrict__ cur, int* __restrict__ csrc) {
    int e = blockIdx.x * blockDim.x + threadIdx.x;
    if (e >= NE) return;
    int pos = atomicAdd(&cur[dstv[e]], 1);
    csrc[pos] = srcv[e];
}

// ====== CSR gather v2, D=256: BLOCK per dst row, LDS index prefetch ======
// 4 waves split the row's sources; lane owns float4 of columns; LDS reduce.
__global__ __launch_bounds__(256) void k_gather256(
    const float* __restrict__ h, const int* __restrict__ rs, const int* __restrict__ csrc,
    const float* __restrict__ norm, const float* __restrict__ bias,
    unsigned short* __restrict__ outh, unsigned short* __restrict__ outl) {
    __shared__ int   sh_s[256];
    __shared__ float sh_ns[256];
    __shared__ float shred[4 * 256];
    const int tid = threadIdx.x;
    const int wv = tid >> 6, l = tid & 63;
    const int row = blockIdx.x;
    const int beg = rs[row], end = rs[row + 1];
    float4 acc = make_float4(0.f, 0.f, 0.f, 0.f);
    for (int base = beg; base < end; base += 256) {
        __syncthreads();
        if (base + tid < end) {
            int s = csrc[base + tid];
            sh_s[tid] = s;
            sh_ns[tid] = norm[s];
        }
        __syncthreads();
        int cnt = min(256, end - base);
        for (int j = wv; j < cnt; j += 4) {
            int s = sh_s[j];
            float ns = sh_ns[j];
            float4 hv = *(const float4*)&h[((long)s << 8) + (l << 2)];
            acc.x += hv.x * ns; acc.y += hv.y * ns; acc.z += hv.z * ns; acc.w += hv.w * ns;
        }
    }
    __syncthreads();
    *(float4*)&shred[wv * 256 + (l << 2)] = acc;
    __syncthreads();
    float val = shred[tid] + shred[256 + tid] + shred[512 + tid] + shred[768 + tid];
    float r = fmaxf(val * norm[row] + bias[tid], 0.f);
    unsigned short hb = f2bf(r);
    outh[((long)row << 8) + tid] = hb;
    outl[((long)row << 8) + tid] = f2bf(r - bf2f(hb));
}

// ====== CSR gather v2, D=128: BLOCK per dst row, LDS index prefetch ======
__global__ __launch_bounds__(256) void k_gather128(
    const float* __restrict__ h, const int* __restrict__ rs, const int* __restrict__ csrc,
    const float* __restrict__ norm, const float* __restrict__ bias,
    float* __restrict__ out) {
    __shared__ int   sh_s[256];
    __shared__ float sh_ns[256];
    __shared__ float shred[4 * 128];
    const int tid = threadIdx.x;
    const int wv = tid >> 6, l = tid & 63;
    const int row = blockIdx.x;
    const int beg = rs[row], end = rs[row + 1];
    float2 acc = make_float2(0.f, 0.f);
    for (int base = beg; base < end; base += 256) {
        __syncthreads();
        if (base + tid < end) {
            int s = csrc[base + tid];
            sh_s[tid] = s;
            sh_ns[tid] = norm[s];
        }
        __syncthreads();
        int cnt = min(256, end - base);
        for (int j = wv; j < cnt; j += 4) {
            int s = sh_s[j];
            float ns = sh_ns[j];
            float2 hv = *(const float2*)&h[((long)s << 7) + (l << 1)];
            acc.x += hv.x * ns; acc.y += hv.y * ns;
        }
    }
    __syncthreads();
    *(float2*)&shred[wv * 128 + (l << 1)] = acc;
    __syncthreads();
    if (tid < 128) {
        float val = shred[tid] + shred[128 + tid] + shred[256 + tid] + shred[384 + tid];
        float r = fmaxf(val * norm[row] + bias[tid], 0.f);
        out[((long)row << 7) + tid] = r;
    }
}

// ------------- attention fusion + classifier (one wave per row) -------------
__global__ __launch_bounds__(256) void k_attn(
    const float* __restrict__ HL, const float* __restrict__ HG,
    const float* __restrict__ Wa, const float* __restrict__ Wc,
    const float* __restrict__ bc, float* __restrict__ out) {
    int wv = threadIdx.x >> 6, l = threadIdx.x & 63;
    int row = blockIdx.x * 4 + wv;
    float2 hl = *(const float2*)&HL[(long)row * DO_ + l * 2];
    float2 hg = *(const float2*)&HG[(long)row * DO_ + l * 2];
    float4 wa0 = *(const float4*)&Wa[(2 * l) * 2];
    float4 wa1 = *(const float4*)&Wa[(DO_ + 2 * l) * 2];
    float p0 = hl.x * wa0.x + hl.y * wa0.z + hg.x * wa1.x + hg.y * wa1.z;
    float p1 = hl.x * wa0.y + hl.y * wa0.w + hg.x * wa1.y + hg.y * wa1.w;
#pragma unroll
    for (int off = 32; off >= 1; off >>= 1) {
        p0 += __shfl_xor(p0, off);
        p1 += __shfl_xor(p1, off);
    }
    float mx = fmaxf(p0, p1);
    float e0 = __expf(p0 - mx), e1 = __expf(p1 - mx);
    float inv = 1.f / (e0 + e1);
    float a0 = e0 * inv, a1 = e1 * inv;
    float z0 = a0 * hl.x + a1 * hg.x;
    float z1 = a0 * hl.y + a1 * hg.y;
    float4 wcA0 = *(const float4*)&Wc[(2 * l) * NCLS];
    float4 wcA1 = *(const float4*)&Wc[(2 * l) * NCLS + 4];
    float4 wcB0 = *(const float4*)&Wc[(2 * l + 1) * NCLS];
    float4 wcB1 = *(const float4*)&Wc[(2 * l + 1) * NCLS + 4];
    float q0 = z0 * wcA0.x + z1 * wcB0.x;
    float q1 = z0 * wcA0.y + z1 * wcB0.y;
    float q2 = z0 * wcA0.z + z1 * wcB0.z;
    float q3 = z0 * wcA0.w + z1 * wcB0.w;
    float q4 = z0 * wcA1.x + z1 * wcB1.x;
    float q5 = z0 * wcA1.y + z1 * wcB1.y;
    float q6 = z0 * wcA1.z + z1 * wcB1.z;
    float q7 = z0 * wcA1.w + z1 * wcB1.w;
#pragma unroll
    for (int off = 32; off >= 1; off >>= 1) {
        q0 += __shfl_xor(q0, off); q1 += __shfl_xor(q1, off);
        q2 += __shfl_xor(q2, off); q3 += __shfl_xor(q3, off);
        q4 += __shfl_xor(q4, off); q5 += __shfl_xor(q5, off);
        q6 += __shfl_xor(q6, off); q7 += __shfl_xor(q7, off);
    }
    if (l == 0) {
        float* o = &out[(long)row * NCLS];
        o[0] = q0 + bc[0]; o[1] = q1 + bc[1]; o[2] = q2 + bc[2]; o[3] = q3 + bc[3];
        o[4] = q4 + bc[4]; o[5] = q5 + bc[5]; o[6] = q6 + bc[6]; o[7] = q7 + bc[7];
    }
}

extern "C" void kernel_launch(void* const* d_in, const int* in_sizes, int n_in,
                              void* d_out, int out_size, void* d_ws, size_t ws_size,
                              hipStream_t stream) {
    (void)in_sizes; (void)n_in; (void)out_size; (void)ws_size;
    const float* feats = (const float*)d_in[0];
    const float* norm  = (const float*)d_in[1];
    const float* tao1L = (const float*)d_in[2];
    const float* tao2L = (const float*)d_in[3];
    const float* tao1G = (const float*)d_in[4];
    const float* tao2G = (const float*)d_in[5];
    const float* PPMI  = (const float*)d_in[6];
    const float* w1  = (const float*)d_in[7];
    const float* b1  = (const float*)d_in[8];
    const float* w2  = (const float*)d_in[9];
    const float* b2  = (const float*)d_in[10];
    const float* w1g = (const float*)d_in[11];
    const float* b1g = (const float*)d_in[12];
    const float* w2g = (const float*)d_in[13];
    const float* b2g = (const float*)d_in[14];
    const float* Wa  = (const float*)d_in[15];
    const float* Wc  = (const float*)d_in[16];
    const float* bc  = (const float*)d_in[17];
    const int* src = (const int*)d_in[18];
    const int* dst = (const int*)d_in[19];

    char* ws = (char*)d_ws;
    size_t off = 0;
    auto alloc = [&](size_t b) { void* p = (void*)(ws + off); off += (b + 255) & ~(size_t)255; return p; };
    unsigned short* ppmi_bf = (unsigned short*)alloc((size_t)NN * NN * 2);     // 134 MB
    unsigned short* fh = (unsigned short*)alloc((size_t)NN * DIN * 2);
    unsigned short* fl = (unsigned short*)alloc((size_t)NN * DIN * 2);
    unsigned short* w1lh = (unsigned short*)alloc((size_t)DH * DIN * 2);
    unsigned short* w1ll = (unsigned short*)alloc((size_t)DH * DIN * 2);
    unsigned short* w2lh = (unsigned short*)alloc((size_t)DO_ * DH * 2);
    unsigned short* w2ll = (unsigned short*)alloc((size_t)DO_ * DH * 2);
    unsigned short* w1gh = (unsigned short*)alloc((size_t)DH * DIN * 2);
    unsigned short* w1gl = (unsigned short*)alloc((size_t)DH * DIN * 2);
    unsigned short* w2gh = (unsigned short*)alloc((size_t)DO_ * DH * 2);
    unsigned short* w2gl = (unsigned short*)alloc((size_t)DO_ * DH * 2);
    unsigned short* g0t = (unsigned short*)alloc((size_t)DH * NN * 2);
    unsigned short* g2h = (unsigned short*)alloc((size_t)NN * DH * 2);
    unsigned short* g2l = (unsigned short*)alloc((size_t)NN * DH * 2);
    unsigned short* g3t = (unsigned short*)alloc((size_t)DO_ * NN * 2);
    unsigned short* h1h = (unsigned short*)alloc((size_t)NN * DH * 2);
    unsigned short* h1l = (unsigned short*)alloc((size_t)NN * DH * 2);
    float* HL  = (float*)alloc((size_t)NN * DO_ * 4);
    float* HG  = (float*)alloc((size_t)NN * DO_ * 4);
    // CSR arrays
    int* deg  = (int*)alloc((size_t)NN * 4);
    int* rs   = (int*)alloc((size_t)(NN + 1) * 4);
    int* cur  = (int*)alloc((size_t)NN * 4);
    int* csrc = (int*)alloc((size_t)NE * 4);
    // big region reused sequentially: local h0/h2 first, then split-K partials
    char* big = (char*)alloc((size_t)8 * NN * DO_ * 4);                        // 33.5 MB
    float* h0 = (float*)big;                         // NN*DH*4 = 8.4 MB
    float* h2 = (float*)(big + (size_t)NN * DH * 4); // NN*DO_*4 = 4.2 MB
    float* part = (float*)big;

    // CSR build (shared by both propagation layers)
    hipMemsetAsync(deg, 0, (size_t)NN * 4, stream);
    k_hist<<<dim3(NE / 256), dim3(256), 0, stream>>>(dst, deg);
    k_scan<<<dim3(1), dim3(1024), 0, stream>>>(deg, rs, cur);
    k_fill<<<dim3(NE / 256), dim3(256), 0, stream>>>(src, dst, cur, csrc);

    // conversions
    k_cvt_bf16<<<dim3(8192), dim3(256), 0, stream>>>(PPMI, ppmi_bf, NN * NN / 4);
    k_cvt_split<<<dim3(2048), dim3(256), 0, stream>>>(feats, fh, fl, NN * DIN / 4);

    // effective weights (split bf16, transposed)
    k_eff_split<<<dim3((DIN * DH + 255) / 256), dim3(256), 0, stream>>>(w1,  tao1L, w1lh, w1ll, DIN, DH, DH);
    k_eff_split<<<dim3((DH * DO_ + 255) / 256), dim3(256), 0, stream>>>(w2,  tao2L, w2lh, w2ll, DH, DO_, DO_);
    k_eff_split<<<dim3((DIN * DH + 255) / 256), dim3(256), 0, stream>>>(w1g, tao1G, w1gh, w1gl, DIN, DH, DH);
    k_eff_split<<<dim3((DH * DO_ + 255) / 256), dim3(256), 0, stream>>>(w2g, tao2G, w2gh, w2gl, DH, DO_, DO_);

    // ---- local branch (all ≈fp32 precision) ----
    k_gemm_split<0><<<dim3(64, 2), dim3(256), 0, stream>>>(fh, fl, w1lh, w1ll, h0, NN, DH, DIN);
    k_gather256<<<dim3(NN), dim3(256), 0, stream>>>(h0, rs, csrc, norm, b1, h1h, h1l);
    k_gemm_split<0><<<dim3(64, 1), dim3(256), 0, stream>>>(h1h, h1l, w2lh, w2ll, h2, NN, DO_, DH);
    k_gather128<<<dim3(NN), dim3(256), 0, stream>>>(h2, rs, csrc, norm, b2, HL);

    // ---- global branch (PPMI GEMMs single-bf16: results are O(0.01), err negligible) ----
    k_gemm_split<2><<<dim3(64, 2), dim3(256), 0, stream>>>(fh, fl, w1gh, w1gl, g0t, NN, DH, DIN);
    k_gemm_part<<<dim3(64, 2, 4), dim3(256), 0, stream>>>(ppmi_bf, g0t, part, NN, DH, NN, NN / 4);
    k_combine<1><<<dim3(NN * DH / 4 / 256), dim3(256), 0, stream>>>(part, g2h, g2l, b1g, NN, DH, 4);
    k_gemm_split<2><<<dim3(64, 1), dim3(256), 0, stream>>>(g2h, g2l, w2gh, w2gl, g3t, NN, DO_, DH);
    k_gemm_part<<<dim3(64, 1, 8), dim3(256), 0, stream>>>(ppmi_bf, g3t, part, NN, DO_, NN, NN / 8);
    k_combine<0><<<dim3(NN * DO_ / 4 / 256), dim3(256), 0, stream>>>(part, HG, nullptr, b2g, NN, DO_, 8);

    // ---- attention fusion + classifier ----
    k_attn<<<dim3(NN / 4), dim3(256), 0, stream>>>(HL, HG, Wa, Wc, bc, (float*)d_out);
}

// Round 6
// 402.129 us; speedup vs baseline: 4.7888x; 1.6523x over previous
//
#include <hip/hip_runtime.h>
#include <hip/hip_bf16.h>

#define NN 8192
#define DIN 512
#define DH 256
#define DO_ 128
#define NCLS 8
#define NE 262144

typedef __attribute__((ext_vector_type(8))) short bf16x8;
typedef __attribute__((ext_vector_type(4))) float f32x4;
typedef __attribute__((ext_vector_type(4))) unsigned short u16x4;
typedef __attribute__((ext_vector_type(8))) unsigned short u16x8;

__device__ __forceinline__ unsigned short f2bf(float x) {
    unsigned int u = __float_as_uint(x);
    return (unsigned short)((u + 0x7FFFu + ((u >> 16) & 1u)) >> 16);
}
__device__ __forceinline__ float bf2f(unsigned short h) {
    return __uint_as_float((unsigned int)h << 16);
}

// ---------- f32 -> split bf16 hi/lo (A = hi + lo, rel err ~2^-17) ----------
__global__ void k_cvt_split(const float* __restrict__ in, unsigned short* __restrict__ hi,
                            unsigned short* __restrict__ lo, int n4) {
    int i = blockIdx.x * blockDim.x + threadIdx.x;
    int stride = gridDim.x * blockDim.x;
    for (; i < n4; i += stride) {
        float4 v = ((const float4*)in)[i];
        u16x4 oh, ol;
        oh.x = f2bf(v.x); ol.x = f2bf(v.x - bf2f(oh.x));
        oh.y = f2bf(v.y); ol.y = f2bf(v.y - bf2f(oh.y));
        oh.z = f2bf(v.z); ol.z = f2bf(v.z - bf2f(oh.z));
        oh.w = f2bf(v.w); ol.w = f2bf(v.w - bf2f(oh.w));
        ((u16x4*)hi)[i] = oh;
        ((u16x4*)lo)[i] = ol;
    }
}

// -- all 4 effective-weight transforms in one launch, selected by blockIdx.y --
// effT[j][i] = sum_k w[i][k]*tao[k][j], split bf16 hi/lo, transposed store.
__device__ __forceinline__ void eff_body(const float* __restrict__ w, const float* __restrict__ tao,
                                         unsigned short* __restrict__ effTh, unsigned short* __restrict__ effTl,
                                         int I, int K0, int J) {
    int idx = blockIdx.x * blockDim.x + threadIdx.x;
    if (idx >= I * J) return;
    int j = idx % J, i = idx / J;
    float s = 0.f;
    for (int k = 0; k < K0; ++k) s += w[i * K0 + k] * tao[k * J + j];
    unsigned short h = f2bf(s);
    effTh[j * I + i] = h;
    effTl[j * I + i] = f2bf(s - bf2f(h));
}

__global__ void k_eff_all(
    const float* w1, const float* t1, unsigned short* h1, unsigned short* l1,
    const float* w2, const float* t2, unsigned short* h2, unsigned short* l2,
    const float* w3, const float* t3, unsigned short* h3, unsigned short* l3,
    const float* w4, const float* t4, unsigned short* h4, unsigned short* l4) {
    switch (blockIdx.y) {
        case 0: eff_body(w1, t1, h1, l1, DIN, DH, DH);   break;
        case 1: eff_body(w2, t2, h2, l2, DH,  DO_, DO_); break;
        case 2: eff_body(w3, t3, h3, l3, DIN, DH, DH);   break;
        default: eff_body(w4, t4, h4, l4, DH, DO_, DO_); break;
    }
}

#define GLDS(gp, lp) __builtin_amdgcn_global_load_lds( \
    (const __attribute__((address_space(1))) void*)(gp), \
    (__attribute__((address_space(3))) void*)(lp), 16, 0, 0)

__device__ __forceinline__ void cvt8_store(unsigned short* dst, float4 a, float4 b) {
    u16x8 o;
    o[0] = f2bf(a.x); o[1] = f2bf(a.y); o[2] = f2bf(a.z); o[3] = f2bf(a.w);
    o[4] = f2bf(b.x); o[5] = f2bf(b.y); o[6] = f2bf(b.z); o[7] = f2bf(b.w);
    *(u16x8*)dst = o;
}

// ======== PPMI GEMM 1: C_part[z] = PPMI(f32,reg-staged) @ g0t^T, BM=128 BN=256 ========
// 512 threads = 8 waves (2x4 of 64x64). A cvt'd f32->bf16 in regs. z-split K.
__global__ __launch_bounds__(512) void k_gemm_ppmi1(
    const float* __restrict__ A, const unsigned short* __restrict__ B,
    float* __restrict__ C, int kPerSplit)
{
    __shared__ unsigned short As[128 * 32];
    __shared__ unsigned short Bs[256 * 32];
    const int t = threadIdx.x;
    const int w = t >> 6;
    const int l = t & 63;
    const int wr = (w >> 2) * 64;
    const int wc = (w & 3) * 64;
    const long row0 = (long)blockIdx.x * 128;
    const long kbeg = (long)blockIdx.z * kPerSplit;
    const int nk = kPerSplit >> 5;
    const int K = NN;

    f32x4 acc[4][4];
#pragma unroll
    for (int mi = 0; mi < 4; ++mi)
#pragma unroll
        for (int ni = 0; ni < 4; ++ni) { f32x4 z = {0.f,0.f,0.f,0.f}; acc[mi][ni] = z; }

    // A staging: r = t>>2 (128 rows), kq = (t&3)*8 -> 2 float4 (8 f32) per thread
    const int ar = t >> 2;
    const int akq = (t & 3) << 3;
    const float* Abase = A + (row0 + ar) * K + kbeg + akq;
    unsigned short* AsW = &As[ar * 32 + akq];
    // B staging: 2 GLDS calls; call c: rows c*128 + w*16 + (l>>2), k off (l&3)*8
    const int srow = (w << 4) + (l >> 2);
    const int skk  = (l & 3) << 3;
    const unsigned short* Bbase = B + (long)srow * K + kbeg + skk;
    unsigned short* BsW = &Bs[(w << 4) * 32];

    for (int kt = 0; kt < nk; ++kt) {
        const long ko = (long)kt << 5;
        __syncthreads();
        float4 fa0 = *(const float4*)(Abase + ko);
        float4 fa1 = *(const float4*)(Abase + ko + 4);
        GLDS(Bbase + ko,                    BsW);
        GLDS(Bbase + (long)128 * K + ko,    BsW + 128 * 32);
        cvt8_store(AsW, fa0, fa1);
        __syncthreads();

        const int ro  = (l & 15);
        const int kof = (l >> 4) << 3;
        bf16x8 a[4], b[4];
#pragma unroll
        for (int mi = 0; mi < 4; ++mi)
            a[mi] = *(const bf16x8*)&As[(wr + mi * 16 + ro) * 32 + kof];
#pragma unroll
        for (int ni = 0; ni < 4; ++ni)
            b[ni] = *(const bf16x8*)&Bs[(wc + ni * 16 + ro) * 32 + kof];
#pragma unroll
        for (int mi = 0; mi < 4; ++mi)
#pragma unroll
            for (int ni = 0; ni < 4; ++ni)
                acc[mi][ni] = __builtin_amdgcn_mfma_f32_16x16x32_bf16(a[mi], b[ni], acc[mi][ni], 0, 0, 0);
    }

    float* Cp = C + (long)blockIdx.z * NN * DH;
#pragma unroll
    for (int mi = 0; mi < 4; ++mi)
#pragma unroll
        for (int ni = 0; ni < 4; ++ni) {
            const long col = wc + ni * 16 + (l & 15);
            const long rbase = row0 + wr + mi * 16 + ((l >> 4) << 2);
            f32x4 v = acc[mi][ni];
#pragma unroll
            for (int j = 0; j < 4; ++j) Cp[(rbase + j) * DH + col] = v[j];
        }
}

// ======== PPMI GEMM 2: C_part[z] = PPMI(f32,reg-staged) @ g3t^T, BM=128 BN=128 ========
// 256 threads = 4 waves. A: 16 f32 per thread -> 2 ds_write_b128.
__global__ __launch_bounds__(256) void k_gemm_ppmi2(
    const float* __restrict__ A, const unsigned short* __restrict__ B,
    float* __restrict__ C, int kPerSplit)
{
    __shared__ unsigned short As[128 * 32];
    __shared__ unsigned short Bs[128 * 32];
    const int t = threadIdx.x;
    const int w = t >> 6;
    const int l = t & 63;
    const int wr = (w >> 1) * 64;
    const int wc = (w & 1) * 64;
    const long row0 = (long)blockIdx.x * 128;
    const long kbeg = (long)blockIdx.z * kPerSplit;
    const int nk = kPerSplit >> 5;
    const int K = NN;

    f32x4 acc[4][4];
#pragma unroll
    for (int mi = 0; mi < 4; ++mi)
#pragma unroll
        for (int ni = 0; ni < 4; ++ni) { f32x4 z = {0.f,0.f,0.f,0.f}; acc[mi][ni] = z; }

    // A staging: r = t>>1 (128 rows), kh = (t&1)*16 -> 4 float4 per thread
    const int ar = t >> 1;
    const int akh = (t & 1) << 4;
    const float* Abase = A + (row0 + ar) * K + kbeg + akh;
    unsigned short* AsW = &As[ar * 32 + akh];
    // B staging: 2 GLDS (4 waves x 16 rows x 2 calls = 128 rows)
    const int srow = (w << 4) + (l >> 2);
    const int skk  = (l & 3) << 3;
    const unsigned short* Bbase = B + (long)srow * K + kbeg + skk;
    unsigned short* BsW = &Bs[w << 9];

    for (int kt = 0; kt < nk; ++kt) {
        const long ko = (long)kt << 5;
        __syncthreads();
        float4 fa0 = *(const float4*)(Abase + ko);
        float4 fa1 = *(const float4*)(Abase + ko + 4);
        float4 fa2 = *(const float4*)(Abase + ko + 8);
        float4 fa3 = *(const float4*)(Abase + ko + 12);
        GLDS(Bbase + ko,                  BsW);
        GLDS(Bbase + (long)64 * K + ko,   BsW + 2048);
        cvt8_store(AsW,     fa0, fa1);
        cvt8_store(AsW + 8, fa2, fa3);
        __syncthreads();

        const int ro  = (l & 15);
        const int kof = (l >> 4) << 3;
        bf16x8 a[4], b[4];
#pragma unroll
        for (int mi = 0; mi < 4; ++mi)
            a[mi] = *(const bf16x8*)&As[(wr + mi * 16 + ro) * 32 + kof];
#pragma unroll
        for (int ni = 0; ni < 4; ++ni)
            b[ni] = *(const bf16x8*)&Bs[(wc + ni * 16 + ro) * 32 + kof];
#pragma unroll
        for (int mi = 0; mi < 4; ++mi)
#pragma unroll
            for (int ni = 0; ni < 4; ++ni)
                acc[mi][ni] = __builtin_amdgcn_mfma_f32_16x16x32_bf16(a[mi], b[ni], acc[mi][ni], 0, 0, 0);
    }

    float* Cp = C + (long)blockIdx.z * NN * DO_;
#pragma unroll
    for (int mi = 0; mi < 4; ++mi)
#pragma unroll
        for (int ni = 0; ni < 4; ++ni) {
            const long col = wc + ni * 16 + (l & 15);
            const long rbase = row0 + wr + mi * 16 + ((l >> 4) << 2);
            f32x4 v = acc[mi][ni];
#pragma unroll
            for (int j = 0; j < 4; ++j) Cp[(rbase + j) * DO_ + col] = v[j];
        }
}

// ------------- split-bf16 3-term MFMA GEMM (≈fp32 precision) -------------
// C = (Ah+Al)@(Bh+Bl)^T dropping Al*Bl. OUT_MODE: 0 = f32 [M,N]; 2 = bf16 [N,M].
template<int OUT_MODE>
__global__ __launch_bounds__(256) void k_gemm_split(
    const unsigned short* __restrict__ Ah, const unsigned short* __restrict__ Al,
    const unsigned short* __restrict__ Bh, const unsigned short* __restrict__ Bl,
    void* __restrict__ C, int M, int N, int K)
{
    __shared__ unsigned short AsH[128 * 32];
    __shared__ unsigned short AsL[128 * 32];
    __shared__ unsigned short BsH[128 * 32];
    __shared__ unsigned short BsL[128 * 32];
    const int t = threadIdx.x;
    const int w = t >> 6;
    const int l = t & 63;
    const int wr = (w >> 1) * 64;
    const int wc = (w & 1) * 64;
    const long row0 = (long)blockIdx.x * 128;
    const long col0 = (long)blockIdx.y * 128;
    const int nk = K >> 5;

    f32x4 acc[4][4];
#pragma unroll
    for (int mi = 0; mi < 4; ++mi)
#pragma unroll
        for (int ni = 0; ni < 4; ++ni) { f32x4 z = {0.f,0.f,0.f,0.f}; acc[mi][ni] = z; }

    const int srow = (w << 4) + (l >> 2);
    const int skk  = (l & 3) << 3;
    const long aoff = row0 * K + skk;
    const long boff = col0 * K + skk;
    unsigned short* AsHW = &AsH[w << 9];
    unsigned short* AsLW = &AsL[w << 9];
    unsigned short* BsHW = &BsH[w << 9];
    unsigned short* BsLW = &BsL[w << 9];

    for (int kt = 0; kt < nk; ++kt) {
        const long ko = (long)kt << 5;
        __syncthreads();
        GLDS(Ah + aoff + (long)srow * K + ko,        AsHW);
        GLDS(Ah + aoff + (long)(srow + 64) * K + ko, AsHW + 2048);
        GLDS(Al + aoff + (long)srow * K + ko,        AsLW);
        GLDS(Al + aoff + (long)(srow + 64) * K + ko, AsLW + 2048);
        GLDS(Bh + boff + (long)srow * K + ko,        BsHW);
        GLDS(Bh + boff + (long)(srow + 64) * K + ko, BsHW + 2048);
        GLDS(Bl + boff + (long)srow * K + ko,        BsLW);
        GLDS(Bl + boff + (long)(srow + 64) * K + ko, BsLW + 2048);
        __syncthreads();

        const int ro  = (l & 15);
        const int kof = (l >> 4) << 3;
        bf16x8 ah[4], al[4], bh[4], bl[4];
#pragma unroll
        for (int mi = 0; mi < 4; ++mi) {
            ah[mi] = *(const bf16x8*)&AsH[(wr + mi * 16 + ro) * 32 + kof];
            al[mi] = *(const bf16x8*)&AsL[(wr + mi * 16 + ro) * 32 + kof];
        }
#pragma unroll
        for (int ni = 0; ni < 4; ++ni) {
            bh[ni] = *(const bf16x8*)&BsH[(wc + ni * 16 + ro) * 32 + kof];
            bl[ni] = *(const bf16x8*)&BsL[(wc + ni * 16 + ro) * 32 + kof];
        }
#pragma unroll
        for (int mi = 0; mi < 4; ++mi)
#pragma unroll
            for (int ni = 0; ni < 4; ++ni) {
                acc[mi][ni] = __builtin_amdgcn_mfma_f32_16x16x32_bf16(ah[mi], bl[ni], acc[mi][ni], 0, 0, 0);
                acc[mi][ni] = __builtin_amdgcn_mfma_f32_16x16x32_bf16(al[mi], bh[ni], acc[mi][ni], 0, 0, 0);
                acc[mi][ni] = __builtin_amdgcn_mfma_f32_16x16x32_bf16(ah[mi], bh[ni], acc[mi][ni], 0, 0, 0);
            }
    }

#pragma unroll
    for (int mi = 0; mi < 4; ++mi)
#pragma unroll
        for (int ni = 0; ni < 4; ++ni) {
            const long col = col0 + wc + ni * 16 + (l & 15);
            const long rbase = row0 + wr + mi * 16 + ((l >> 4) << 2);
            f32x4 v = acc[mi][ni];
            if (OUT_MODE == 0) {
                float* Cp = (float*)C;
#pragma unroll
                for (int j = 0; j < 4; ++j) Cp[(rbase + j) * N + col] = v[j];
            } else {
                u16x4 o;
                o.x = f2bf(v[0]); o.y = f2bf(v[1]); o.z = f2bf(v[2]); o.w = f2bf(v[3]);
                *(u16x4*)((unsigned short*)C + col * M + rbase) = o;
            }
        }
}

// ------------- split-K combine: sum partials, +bias, relu -------------
template<int OM>
__global__ void k_combine(const float* __restrict__ part, void* __restrict__ out,
                          void* __restrict__ out2, const float* __restrict__ bias,
                          int M, int N, int Z) {
    int idx = blockIdx.x * blockDim.x + threadIdx.x;
    int n4 = N >> 2;
    if (idx >= M * n4) return;
    int m = idx / n4, c = idx % n4;
    float4 s = make_float4(0.f, 0.f, 0.f, 0.f);
    for (int z = 0; z < Z; ++z) {
        float4 p = *(const float4*)&part[((long)z * M + m) * N + (c << 2)];
        s.x += p.x; s.y += p.y; s.z += p.z; s.w += p.w;
    }
    float4 b = *(const float4*)&bias[c << 2];
    s.x = fmaxf(s.x + b.x, 0.f);
    s.y = fmaxf(s.y + b.y, 0.f);
    s.z = fmaxf(s.z + b.z, 0.f);
    s.w = fmaxf(s.w + b.w, 0.f);
    if (OM == 0) {
        *(float4*)((float*)out + (long)m * N + (c << 2)) = s;
    } else {
        u16x4 oh, ol;
        oh.x = f2bf(s.x); ol.x = f2bf(s.x - bf2f(oh.x));
        oh.y = f2bf(s.y); ol.y = f2bf(s.y - bf2f(oh.y));
        oh.z = f2bf(s.z); ol.z = f2bf(s.z - bf2f(oh.z));
        oh.w = f2bf(s.w); ol.w = f2bf(s.w - bf2f(oh.w));
        *(u16x4*)((unsigned short*)out  + (long)m * N + (c << 2)) = oh;
        *(u16x4*)((unsigned short*)out2 + (long)m * N + (c << 2)) = ol;
    }
}

// ================= CSR build: histogram -> scan -> fill =================
__global__ void k_hist(const int* __restrict__ dstv, int* __restrict__ deg) {
    int e = blockIdx.x * blockDim.x + threadIdx.x;
    if (e < NE) atomicAdd(&deg[dstv[e]], 1);
}

__global__ __launch_bounds__(1024) void k_scan(const int* __restrict__ deg,
                                               int* __restrict__ rs, int* __restrict__ cur) {
    __shared__ int sums[1024];
    int t = threadIdx.x;
    int loc[8];
    int s = 0;
#pragma unroll
    for (int j = 0; j < 8; ++j) { loc[j] = deg[t * 8 + j]; s += loc[j]; }
    sums[t] = s;
    __syncthreads();
    for (int off = 1; off < 1024; off <<= 1) {
        int v = (t >= off) ? sums[t - off] : 0;
        __syncthreads();
        sums[t] += v;
        __syncthreads();
    }
    int base = (t > 0) ? sums[t - 1] : 0;
#pragma unroll
    for (int j = 0; j < 8; ++j) {
        rs[t * 8 + j] = base;
        cur[t * 8 + j] = base;
        base += loc[j];
    }
    if (t == 1023) rs[8192] = base;
}

__global__ void k_fill(const int* __restrict__ srcv, const int* __restrict__ dstv,
                       int* __restrict__ cur, int* __restrict__ csrc) {
    int e = blockIdx.x * blockDim.x + threadIdx.x;
    if (e >= NE) return;
    int pos = atomicAdd(&cur[dstv[e]], 1);
    csrc[pos] = srcv[e];
}

// ====== CSR gather, D=256: BLOCK per dst row, LDS index prefetch ======
__global__ __launch_bounds__(256) void k_gather256(
    const float* __restrict__ h, const int* __restrict__ rs, const int* __restrict__ csrc,
    const float* __restrict__ norm, const float* __restrict__ bias,
    unsigned short* __restrict__ outh, unsigned short* __restrict__ outl) {
    __shared__ int   sh_s[256];
    __shared__ float sh_ns[256];
    __shared__ float shred[4 * 256];
    const int tid = threadIdx.x;
    const int wv = tid >> 6, l = tid & 63;
    const int row = blockIdx.x;
    const int beg = rs[row], end = rs[row + 1];
    float4 acc = make_float4(0.f, 0.f, 0.f, 0.f);
    for (int base = beg; base < end; base += 256) {
        __syncthreads();
        if (base + tid < end) {
            int s = csrc[base + tid];
            sh_s[tid] = s;
            sh_ns[tid] = norm[s];
        }
        __syncthreads();
        int cnt = min(256, end - base);
        for (int j = wv; j < cnt; j += 4) {
            int s = sh_s[j];
            float ns = sh_ns[j];
            float4 hv = *(const float4*)&h[((long)s << 8) + (l << 2)];
            acc.x += hv.x * ns; acc.y += hv.y * ns; acc.z += hv.z * ns; acc.w += hv.w * ns;
        }
    }
    __syncthreads();
    *(float4*)&shred[wv * 256 + (l << 2)] = acc;
    __syncthreads();
    float val = shred[tid] + shred[256 + tid] + shred[512 + tid] + shred[768 + tid];
    float r = fmaxf(val * norm[row] + bias[tid], 0.f);
    unsigned short hb = f2bf(r);
    outh[((long)row << 8) + tid] = hb;
    outl[((long)row << 8) + tid] = f2bf(r - bf2f(hb));
}

// ====== CSR gather, D=128: BLOCK per dst row, LDS index prefetch ======
__global__ __launch_bounds__(256) void k_gather128(
    const float* __restrict__ h, const int* __restrict__ rs, const int* __restrict__ csrc,
    const float* __restrict__ norm, const float* __restrict__ bias,
    float* __restrict__ out) {
    __shared__ int   sh_s[256];
    __shared__ float sh_ns[256];
    __shared__ float shred[4 * 128];
    const int tid = threadIdx.x;
    const int wv = tid >> 6, l = tid & 63;
    const int row = blockIdx.x;
    const int beg = rs[row], end = rs[row + 1];
    float2 acc = make_float2(0.f, 0.f);
    for (int base = beg; base < end; base += 256) {
        __syncthreads();
        if (base + tid < end) {
            int s = csrc[base + tid];
            sh_s[tid] = s;
            sh_ns[tid] = norm[s];
        }
        __syncthreads();
        int cnt = min(256, end - base);
        for (int j = wv; j < cnt; j += 4) {
            int s = sh_s[j];
            float ns = sh_ns[j];
            float2 hv = *(const float2*)&h[((long)s << 7) + (l << 1)];
            acc.x += hv.x * ns; acc.y += hv.y * ns;
        }
    }
    __syncthreads();
    *(float2*)&shred[wv * 128 + (l << 1)] = acc;
    __syncthreads();
    if (tid < 128) {
        float val = shred[tid] + shred[128 + tid] + shred[256 + tid] + shred[384 + tid];
        float r = fmaxf(val * norm[row] + bias[tid], 0.f);
        out[((long)row << 7) + tid] = r;
    }
}

// ------------- attention fusion + classifier (one wave per row) -------------
__global__ __launch_bounds__(256) void k_attn(
    const float* __restrict__ HL, const float* __restrict__ HG,
    const float* __restrict__ Wa, const float* __restrict__ Wc,
    const float* __restrict__ bc, float* __restrict__ out) {
    int wv = threadIdx.x >> 6, l = threadIdx.x & 63;
    int row = blockIdx.x * 4 + wv;
    float2 hl = *(const float2*)&HL[(long)row * DO_ + l * 2];
    float2 hg = *(const float2*)&HG[(long)row * DO_ + l * 2];
    float4 wa0 = *(const float4*)&Wa[(2 * l) * 2];
    float4 wa1 = *(const float4*)&Wa[(DO_ + 2 * l) * 2];
    float p0 = hl.x * wa0.x + hl.y * wa0.z + hg.x * wa1.x + hg.y * wa1.z;
    float p1 = hl.x * wa0.y + hl.y * wa0.w + hg.x * wa1.y + hg.y * wa1.w;
#pragma unroll
    for (int off = 32; off >= 1; off >>= 1) {
        p0 += __shfl_xor(p0, off);
        p1 += __shfl_xor(p1, off);
    }
    float mx = fmaxf(p0, p1);
    float e0 = __expf(p0 - mx), e1 = __expf(p1 - mx);
    float inv = 1.f / (e0 + e1);
    float a0 = e0 * inv, a1 = e1 * inv;
    float z0 = a0 * hl.x + a1 * hg.x;
    float z1 = a0 * hl.y + a1 * hg.y;
    float4 wcA0 = *(const float4*)&Wc[(2 * l) * NCLS];
    float4 wcA1 = *(const float4*)&Wc[(2 * l) * NCLS + 4];
    float4 wcB0 = *(const float4*)&Wc[(2 * l + 1) * NCLS];
    float4 wcB1 = *(const float4*)&Wc[(2 * l + 1) * NCLS + 4];
    float q0 = z0 * wcA0.x + z1 * wcB0.x;
    float q1 = z0 * wcA0.y + z1 * wcB0.y;
    float q2 = z0 * wcA0.z + z1 * wcB0.z;
    float q3 = z0 * wcA0.w + z1 * wcB0.w;
    float q4 = z0 * wcA1.x + z1 * wcB1.x;
    float q5 = z0 * wcA1.y + z1 * wcB1.y;
    float q6 = z0 * wcA1.z + z1 * wcB1.z;
    float q7 = z0 * wcA1.w + z1 * wcB1.w;
#pragma unroll
    for (int off = 32; off >= 1; off >>= 1) {
        q0 += __shfl_xor(q0, off); q1 += __shfl_xor(q1, off);
        q2 += __shfl_xor(q2, off); q3 += __shfl_xor(q3, off);
        q4 += __shfl_xor(q4, off); q5 += __shfl_xor(q5, off);
        q6 += __shfl_xor(q6, off); q7 += __shfl_xor(q7, off);
    }
    if (l == 0) {
        float* o = &out[(long)row * NCLS];
        o[0] = q0 + bc[0]; o[1] = q1 + bc[1]; o[2] = q2 + bc[2]; o[3] = q3 + bc[3];
        o[4] = q4 + bc[4]; o[5] = q5 + bc[5]; o[6] = q6 + bc[6]; o[7] = q7 + bc[7];
    }
}

extern "C" void kernel_launch(void* const* d_in, const int* in_sizes, int n_in,
                              void* d_out, int out_size, void* d_ws, size_t ws_size,
                              hipStream_t stream) {
    (void)in_sizes; (void)n_in; (void)out_size; (void)ws_size;
    const float* feats = (const float*)d_in[0];
    const float* norm  = (const float*)d_in[1];
    const float* tao1L = (const float*)d_in[2];
    const float* tao2L = (const float*)d_in[3];
    const float* tao1G = (const float*)d_in[4];
    const float* tao2G = (const float*)d_in[5];
    const float* PPMI  = (const float*)d_in[6];
    const float* w1  = (const float*)d_in[7];
    const float* b1  = (const float*)d_in[8];
    const float* w2  = (const float*)d_in[9];
    const float* b2  = (const float*)d_in[10];
    const float* w1g = (const float*)d_in[11];
    const float* b1g = (const float*)d_in[12];
    const float* w2g = (const float*)d_in[13];
    const float* b2g = (const float*)d_in[14];
    const float* Wa  = (const float*)d_in[15];
    const float* Wc  = (const float*)d_in[16];
    const float* bc  = (const float*)d_in[17];
    const int* src = (const int*)d_in[18];
    const int* dst = (const int*)d_in[19];

    char* ws = (char*)d_ws;
    size_t off = 0;
    auto alloc = [&](size_t b) { void* p = (void*)(ws + off); off += (b + 255) & ~(size_t)255; return p; };
    unsigned short* fh = (unsigned short*)alloc((size_t)NN * DIN * 2);
    unsigned short* fl = (unsigned short*)alloc((size_t)NN * DIN * 2);
    unsigned short* w1lh = (unsigned short*)alloc((size_t)DH * DIN * 2);
    unsigned short* w1ll = (unsigned short*)alloc((size_t)DH * DIN * 2);
    unsigned short* w2lh = (unsigned short*)alloc((size_t)DO_ * DH * 2);
    unsigned short* w2ll = (unsigned short*)alloc((size_t)DO_ * DH * 2);
    unsigned short* w1gh = (unsigned short*)alloc((size_t)DH * DIN * 2);
    unsigned short* w1gl = (unsigned short*)alloc((size_t)DH * DIN * 2);
    unsigned short* w2gh = (unsigned short*)alloc((size_t)DO_ * DH * 2);
    unsigned short* w2gl = (unsigned short*)alloc((size_t)DO_ * DH * 2);
    unsigned short* g0t = (unsigned short*)alloc((size_t)DH * NN * 2);
    unsigned short* g2h = (unsigned short*)alloc((size_t)NN * DH * 2);
    unsigned short* g2l = (unsigned short*)alloc((size_t)NN * DH * 2);
    unsigned short* g3t = (unsigned short*)alloc((size_t)DO_ * NN * 2);
    unsigned short* h1h = (unsigned short*)alloc((size_t)NN * DH * 2);
    unsigned short* h1l = (unsigned short*)alloc((size_t)NN * DH * 2);
    float* HL  = (float*)alloc((size_t)NN * DO_ * 4);
    float* HG  = (float*)alloc((size_t)NN * DO_ * 4);
    // CSR arrays
    int* deg  = (int*)alloc((size_t)NN * 4);
    int* rs   = (int*)alloc((size_t)(NN + 1) * 4);
    int* cur  = (int*)alloc((size_t)NN * 4);
    int* csrc = (int*)alloc((size_t)NE * 4);
    // big region: holds h0/h2 (local branch), then split-K partials (global branch)
    char* big = (char*)alloc((size_t)8 * NN * DH * 4);                         // 67 MB
    float* h0 = (float*)big;                         // NN*DH*4 = 8.4 MB
    float* h2 = (float*)(big + (size_t)NN * DH * 4); // NN*DO_*4 = 4.2 MB
    float* part = (float*)big;

    // CSR build (shared by both propagation layers)
    hipMemsetAsync(deg, 0, (size_t)NN * 4, stream);
    k_hist<<<dim3(NE / 256), dim3(256), 0, stream>>>(dst, deg);
    k_scan<<<dim3(1), dim3(1024), 0, stream>>>(deg, rs, cur);
    k_fill<<<dim3(NE / 256), dim3(256), 0, stream>>>(src, dst, cur, csrc);

    // conversions + effective weights (one launch each)
    k_cvt_split<<<dim3(2048), dim3(256), 0, stream>>>(feats, fh, fl, NN * DIN / 4);
    k_eff_all<<<dim3(512, 4), dim3(256), 0, stream>>>(
        w1,  tao1L, w1lh, w1ll,
        w2,  tao2L, w2lh, w2ll,
        w1g, tao1G, w1gh, w1gl,
        w2g, tao2G, w2gh, w2gl);

    // ---- local branch (all ≈fp32 precision) ----
    k_gemm_split<0><<<dim3(64, 2), dim3(256), 0, stream>>>(fh, fl, w1lh, w1ll, h0, NN, DH, DIN);
    k_gather256<<<dim3(NN), dim3(256), 0, stream>>>(h0, rs, csrc, norm, b1, h1h, h1l);
    k_gemm_split<0><<<dim3(64, 1), dim3(256), 0, stream>>>(h1h, h1l, w2lh, w2ll, h2, NN, DO_, DH);
    k_gather128<<<dim3(NN), dim3(256), 0, stream>>>(h2, rs, csrc, norm, b2, HL);

    // ---- global branch: PPMI read as f32 directly (reg-staged cvt), each read ONCE ----
    k_gemm_split<2><<<dim3(64, 2), dim3(256), 0, stream>>>(fh, fl, w1gh, w1gl, g0t, NN, DH, DIN);
    k_gemm_ppmi1<<<dim3(64, 1, 8), dim3(512), 0, stream>>>(PPMI, g0t, part, NN / 8);
    k_combine<1><<<dim3(NN * DH / 4 / 256), dim3(256), 0, stream>>>(part, g2h, g2l, b1g, NN, DH, 8);
    k_gemm_split<2><<<dim3(64, 1), dim3(256), 0, stream>>>(g2h, g2l, w2gh, w2gl, g3t, NN, DO_, DH);
    k_gemm_ppmi2<<<dim3(64, 1, 8), dim3(256), 0, stream>>>(PPMI, g3t, part, NN / 8);
    k_combine<0><<<dim3(NN * DO_ / 4 / 256), dim3(256), 0, stream>>>(part, HG, nullptr, b2g, NN, DO_, 8);

    // ---- attention fusion + classifier ----
    k_attn<<<dim3(NN / 4), dim3(256), 0, stream>>>(HL, HG, Wa, Wc, bc, (float*)d_out);
}